// Round 3
// baseline (3885.006 us; speedup 1.0000x reference)
//
#include <hip/hip_runtime.h>
#include <hip/hip_bf16.h>
#include <math.h>

// Model dims
#define Bq   16
#define Tq   128
#define Hq   512
#define Dq   256
#define G4H  2048            // 4*H
#define MR   2048            // B*T rows
#define VO   32001           // VOUT+1
#define NPAD 32128           // VO padded to multiple of 128
#define NBLK 32              // persistent blocks for recurrence
#define BH   (Bq * Hq)       // 8192
#define HPAIR 4096           // BH/2 u32 pairs per plane

typedef unsigned int u32;
typedef unsigned long long u64;
typedef __attribute__((ext_vector_type(4))) float f32x4;
typedef __attribute__((ext_vector_type(8))) short bfrag;   // 8 x bf16 (4 VGPRs)
typedef __attribute__((ext_vector_type(4))) float facc;    // mfma accumulator

__device__ __forceinline__ float bf2f(short s) {
  union { unsigned u; float f; } v; v.u = ((unsigned)(unsigned short)s) << 16; return v.f;
}
__device__ __forceinline__ short f2bf(float f) {
  union { float f; unsigned u; } v; v.f = f;
  unsigned r = (v.u + 0x7fffu + ((v.u >> 16) & 1u)) >> 16;
  return (short)r;
}
__device__ __forceinline__ float sigm(float x) { return 1.0f / (1.0f + expf(-x)); }

__device__ __forceinline__ void ic_store(u32* p, u32 v) {
  __hip_atomic_store(p, v, __ATOMIC_RELAXED, __HIP_MEMORY_SCOPE_AGENT);
}
__device__ __forceinline__ u64 ic_load64(const u64* p) {
  return __hip_atomic_load(p, __ATOMIC_RELAXED, __HIP_MEMORY_SCOPE_AGENT);
}

// ---------------- IC flag barrier: NO L2 writeback/invalidate (round-2 killer).
// All cross-block data moves via sc0sc1 (agent-atomic) ops that are coherent at
// the Infinity Cache; ordering producer->flag is s_waitcnt vmcnt(0).
__device__ __forceinline__ void icbar(u32* flags, u32 phase) {
  __syncthreads();                                  // block's stores issued
  asm volatile("s_waitcnt vmcnt(0)" ::: "memory");  // sc-stores ack'd at IC
  const int tid = threadIdx.x;
  if (tid == 0)
    __hip_atomic_store(&flags[blockIdx.x * 32], phase, __ATOMIC_RELAXED, __HIP_MEMORY_SCOPE_AGENT);
  if (tid < NBLK) {
    while (__hip_atomic_load(&flags[tid * 32], __ATOMIC_RELAXED, __HIP_MEMORY_SCOPE_AGENT) < phase)
      __builtin_amdgcn_s_sleep(1);
  }
  __syncthreads();
}

// ---------------- transpose + f32->bf16 (+ optional gate-interleave col perm)
__global__ __launch_bounds__(256) void k_transcvt(const float* __restrict__ in,
                                                  short* __restrict__ out,
                                                  int R, int N, int perm) {
  __shared__ float tile[32][33];
  int nb = blockIdx.x * 32, rb = blockIdx.y * 32;
  int tx = threadIdx.x & 31, ty = threadIdx.x >> 5;
  for (int i = 0; i < 4; ++i) {
    int r = rb + ty + i * 8;
    int n = nb + tx;
    tile[ty + i * 8][tx] = (n < N) ? in[(size_t)r * N + n] : 0.0f;
  }
  __syncthreads();
  for (int i = 0; i < 4; ++i) {
    int n = nb + ty + i * 8;
    int orow = perm ? (((n & 511) << 2) | (n >> 9)) : n;
    out[(size_t)orow * R + rb + tx] = f2bf(tile[tx][ty + i * 8]);
  }
}

// ---------------- flat f32 -> bf16
__global__ __launch_bounds__(256) void k_cvt(const float* __restrict__ in,
                                             short* __restrict__ out, int n) {
  int i = (blockIdx.x * 256 + threadIdx.x) * 4;
  if (i + 3 < n) {
    f32x4 v = *(const f32x4*)(in + i);
    short4 o;
    o.x = f2bf(v[0]); o.y = f2bf(v[1]); o.z = f2bf(v[2]); o.w = f2bf(v[3]);
    *(short4*)(out + i) = o;
  }
}

// ---------------- embedding gather -> x_bf [T*B, D] bf16
__global__ __launch_bounds__(256) void k_gather(const int* __restrict__ tokens,
                                                const float* __restrict__ emb,
                                                short* __restrict__ xbf) {
  int row = blockIdx.x;                 // t*16+b
  int t = row >> 4, b = row & 15;
  int tok = tokens[b * Tq + t];
  xbf[(size_t)row * Dq + threadIdx.x] = f2bf(emb[(size_t)tok * Dq + threadIdx.x]);
}

// ---------------- bf16 MFMA GEMM: C[M,ldc] = A[M,K] @ BT[Npad,K]^T + bias
__global__ __launch_bounds__(256) void k_gemm(const short* __restrict__ A,
                                              const short* __restrict__ BT,
                                              float* __restrict__ C,
                                              const float* __restrict__ bias,
                                              int M, int Nreal, int K, int ldc,
                                              int permb) {
  __shared__ short lA[128 * 64];
  __shared__ short lB[128 * 64];
  const int tid = threadIdx.x;
  const int wave = tid >> 6, lane = tid & 63;
  const int l15 = lane & 15, l4 = lane >> 4;
  const int m0 = blockIdx.y * 128, n0 = blockIdx.x * 128;
  const int wm = (wave >> 1) * 64, wn = (wave & 1) * 64;
  facc acc[4][4] = {};

  for (int k0 = 0; k0 < K; k0 += 64) {
    __syncthreads();
    for (int i = 0; i < 4; ++i) {
      int c = i * 256 + wave * 64 + lane;
      int r = c >> 3, q = c & 7;
      int qs = q ^ (r & 7);
      const short* ga = A + (size_t)(m0 + r) * K + k0 + qs * 8;
      const short* gb = BT + (size_t)(n0 + r) * K + k0 + qs * 8;
      short* la = lA + (size_t)(i * 256 + wave * 64) * 8;
      short* lb = lB + (size_t)(i * 256 + wave * 64) * 8;
      __builtin_amdgcn_global_load_lds((const __attribute__((address_space(1))) u32*)ga,
                                       (__attribute__((address_space(3))) u32*)la, 16, 0, 0);
      __builtin_amdgcn_global_load_lds((const __attribute__((address_space(1))) u32*)gb,
                                       (__attribute__((address_space(3))) u32*)lb, 16, 0, 0);
    }
    __syncthreads();
    for (int ks = 0; ks < 2; ++ks) {
      bfrag a[4], b[4];
      for (int mi = 0; mi < 4; ++mi) {
        int r = wm + mi * 16 + l15;
        int qs = (ks * 4 + l4) ^ (r & 7);
        a[mi] = *(const bfrag*)&lA[r * 64 + qs * 8];
      }
      for (int ni = 0; ni < 4; ++ni) {
        int r = wn + ni * 16 + l15;
        int qs = (ks * 4 + l4) ^ (r & 7);
        b[ni] = *(const bfrag*)&lB[r * 64 + qs * 8];
      }
      for (int mi = 0; mi < 4; ++mi)
        for (int ni = 0; ni < 4; ++ni)
          acc[mi][ni] = __builtin_amdgcn_mfma_f32_16x16x32_bf16(a[mi], b[ni], acc[mi][ni], 0, 0, 0);
    }
  }
  for (int ni = 0; ni < 4; ++ni) {
    int col = n0 + wn + ni * 16 + l15;
    if (col >= Nreal) continue;
    int bcol = permb ? (((col & 3) << 9) | (col >> 2)) : col;
    float bs = bias ? bias[bcol] : 0.0f;
    for (int mi = 0; mi < 4; ++mi) {
      int rb = m0 + wm + mi * 16 + l4 * 4;
      facc v = acc[mi][ni];
      C[(size_t)(rb + 0) * ldc + col] = v[0] + bs;
      C[(size_t)(rb + 1) * ldc + col] = v[1] + bs;
      C[(size_t)(rb + 2) * ldc + col] = v[2] + bs;
      C[(size_t)(rb + 3) * ldc + col] = v[3] + bs;
    }
  }
}

// h buffer layout (per state): u32 hbuf[2 parity][2 plane(hi,lo)][HPAIR]
// pair index for (bb,col) = (bb*512+col)/2; low half = even col.

// ---------------- single-cell LSTM recurrence (persistent, NBLK x 256)
__global__ __launch_bounds__(256) void k_rec(const float* __restrict__ XW,
                                             const short* __restrict__ UT,
                                             const float* __restrict__ hinit,
                                             const float* __restrict__ cinit,
                                             u32* __restrict__ hbuf,
                                             float* __restrict__ hfin,
                                             float* __restrict__ cfin,
                                             short* __restrict__ seq_bf,
                                             float* __restrict__ seq_f32,
                                             u32* flags) {
  __shared__ short lh[2][16][520];
  __shared__ float zt[4][16][20];
  const int tid = threadIdx.x;
  const int wv = tid >> 6, lane = tid & 63;
  const int l15 = lane & 15, l4 = lane >> 4;
  const int gw = blockIdx.x * 4 + wv;          // 0..127: owns h cols [4gw,4gw+4)
  const int bb = lane >> 2, jj = lane & 3;
  const int hidx = gw * 4 + jj;

  float c = cinit ? cinit[bb * Hq + hidx] : 0.0f;
  {
    float hv = hinit ? hinit[bb * Hq + hidx] : 0.0f;
    int hi_ = (int)(unsigned short)f2bf(hv);
    int lo_ = (int)(unsigned short)f2bf(hv - bf2f((short)hi_));
    int hi2 = __shfl_xor(hi_, 1), lo2 = __shfl_xor(lo_, 1);
    if ((jj & 1) == 0) {
      int pi = (bb * Hq + hidx) >> 1;
      ic_store(&hbuf[pi], (u32)hi_ | ((u32)hi2 << 16));
      ic_store(&hbuf[HPAIR + pi], (u32)lo_ | ((u32)lo2 << 16));
    }
  }
  icbar(flags, 1);

  const short* ub = UT + (size_t)(gw * 16 + l15) * Hq + l4 * 8;

  for (int s = 0; s < Tq; ++s) {
    const u64* hsrc = (const u64*)(hbuf + (size_t)(s & 1) * 2 * HPAIR);
    #pragma unroll
    for (int it = 0; it < 16; ++it) {        // 4096 ulongs = 2 planes x 16 x 512
      int i = it * 256 + tid;
      int p = i >> 11, rem = i & 2047, r = rem >> 7, cb = (rem & 127) * 4;
      u64 v = ic_load64(hsrc + i);
      *(u64*)&lh[p][r][cb] = v;
    }
    __syncthreads();
    facc a0 = {}, a1 = {};
    #pragma unroll
    for (int ks = 0; ks < 16; ++ks) {
      bfrag bu = *(const bfrag*)&ub[ks * 32];
      bfrag ah = *(const bfrag*)&lh[0][l15][ks * 32 + l4 * 8];
      bfrag al = *(const bfrag*)&lh[1][l15][ks * 32 + l4 * 8];
      a0 = __builtin_amdgcn_mfma_f32_16x16x32_bf16(ah, bu, a0, 0, 0, 0);
      a1 = __builtin_amdgcn_mfma_f32_16x16x32_bf16(al, bu, a1, 0, 0, 0);
    }
    a0 += a1;
    *(f32x4*)&zt[wv][l15][l4 * 4] = a0;
    __syncthreads();
    {
      f32x4 xg = *(const f32x4*)&XW[(size_t)(s * Bq + bb) * G4H + hidx * 4];
      float zi = zt[wv][4 * jj + 0][bb] + xg[0];
      float zf = zt[wv][4 * jj + 1][bb] + xg[1];
      float zg = zt[wv][4 * jj + 2][bb] + xg[2];
      float zo = zt[wv][4 * jj + 3][bb] + xg[3];
      c = sigm(zf) * c + sigm(zi) * tanhf(zg);
      float hN = sigm(zo) * tanhf(c);
      int hi_ = (int)(unsigned short)f2bf(hN);
      int lo_ = (int)(unsigned short)f2bf(hN - bf2f((short)hi_));
      int hi2 = __shfl_xor(hi_, 1), lo2 = __shfl_xor(lo_, 1);
      if ((jj & 1) == 0) {
        int pi = (bb * Hq + hidx) >> 1;
        u32* dst = hbuf + (size_t)((s + 1) & 1) * 2 * HPAIR + pi;
        ic_store(dst, (u32)hi_ | ((u32)hi2 << 16));
        ic_store(dst + HPAIR, (u32)lo_ | ((u32)lo2 << 16));
      }
      seq_bf[(size_t)(s * Bq + bb) * Hq + hidx] = (short)hi_;
      if (seq_f32) seq_f32[(size_t)(s * Bq + bb) * Hq + hidx] = hN;
      if (s == Tq - 1) { hfin[bb * Hq + hidx] = hN; cfin[bb * Hq + hidx] = c; }
    }
    icbar(flags, (u32)(s + 2));
  }
}

// ---------------- decoder: cells A and B skewed (phase p: A(p) and B(p-1))
__global__ __launch_bounds__(256) void k_dec2(const float* __restrict__ XW,
                                              const short* __restrict__ U1T,   // Ud1'
                                              const short* __restrict__ W2T,   // Wd2'
                                              const short* __restrict__ U2T,   // Ud2'
                                              const float* __restrict__ bd2,
                                              const float* __restrict__ h1f, const float* __restrict__ c1f,
                                              const float* __restrict__ h2f, const float* __restrict__ c2f,
                                              u32* __restrict__ hAbuf, u32* __restrict__ hBbuf,
                                              float* __restrict__ hBseq, float* __restrict__ decb,
                                              u32* flags) {
  __shared__ short lA[2][16][520];
  __shared__ short lB[2][16][520];
  __shared__ float zt[4][16][20];
  const int tid = threadIdx.x;
  const int wv = tid >> 6, lane = tid & 63;
  const int l15 = lane & 15, l4 = lane >> 4;
  const int gw = blockIdx.x * 4 + wv;
  const int bb = lane >> 2, jj = lane & 3;
  const int hidx = gw * 4 + jj;

  float cAr = c1f[bb * Hq + hidx], cBr = c2f[bb * Hq + hidx];
  {
    float ha = h1f[bb * Hq + hidx], hbv = h2f[bb * Hq + hidx];
    int ahi = (int)(unsigned short)f2bf(ha);
    int alo = (int)(unsigned short)f2bf(ha - bf2f((short)ahi));
    int bhi = (int)(unsigned short)f2bf(hbv);
    int blo = (int)(unsigned short)f2bf(hbv - bf2f((short)bhi));
    int ahi2 = __shfl_xor(ahi, 1), alo2 = __shfl_xor(alo, 1);
    int bhi2 = __shfl_xor(bhi, 1), blo2 = __shfl_xor(blo, 1);
    if ((jj & 1) == 0) {
      int pi = (bb * Hq + hidx) >> 1;
      u32 ah = (u32)ahi | ((u32)ahi2 << 16), al = (u32)alo | ((u32)alo2 << 16);
      u32 bh = (u32)bhi | ((u32)bhi2 << 16), bl = (u32)blo | ((u32)blo2 << 16);
      for (int par = 0; par < 2; ++par) {
        u32* da = hAbuf + (size_t)par * 2 * HPAIR + pi;
        u32* db = hBbuf + (size_t)par * 2 * HPAIR + pi;
        ic_store(da, ah); ic_store(da + HPAIR, al);
        ic_store(db, bh); ic_store(db + HPAIR, bl);
      }
    }
  }
  float bdi = bd2[hidx], bdf = bd2[Hq + hidx], bdg = bd2[2 * Hq + hidx], bdo = bd2[3 * Hq + hidx];
  icbar(flags, 1);

  const short* u1b = U1T + (size_t)(gw * 16 + l15) * Hq + l4 * 8;
  const short* w2b = W2T + (size_t)(gw * 16 + l15) * Hq + l4 * 8;
  const short* u2b = U2T + (size_t)(gw * 16 + l15) * Hq + l4 * 8;

  for (int p = 0; p <= Tq; ++p) {
    const u64* asrc = (const u64*)(hAbuf + (size_t)(p & 1) * 2 * HPAIR);
    const u64* bsrc = (const u64*)(hBbuf + (size_t)(p & 1) * 2 * HPAIR);
    #pragma unroll
    for (int it = 0; it < 16; ++it) {
      int i = it * 256 + tid;
      int pp = i >> 11, rem = i & 2047, r = rem >> 7, cb = (rem & 127) * 4;
      u64 va = ic_load64(asrc + i);
      u64 vb = ic_load64(bsrc + i);
      *(u64*)&lA[pp][r][cb] = va;
      *(u64*)&lB[pp][r][cb] = vb;
    }
    __syncthreads();

    facc a0 = {}, a1 = {}, b0 = {}, b1 = {}, b2a = {}, b3 = {};
    if (p < Tq) {
      #pragma unroll
      for (int ks = 0; ks < 16; ++ks) {
        bfrag u = *(const bfrag*)&u1b[ks * 32];
        bfrag ah = *(const bfrag*)&lA[0][l15][ks * 32 + l4 * 8];
        bfrag al = *(const bfrag*)&lA[1][l15][ks * 32 + l4 * 8];
        a0 = __builtin_amdgcn_mfma_f32_16x16x32_bf16(ah, u, a0, 0, 0, 0);
        a1 = __builtin_amdgcn_mfma_f32_16x16x32_bf16(al, u, a1, 0, 0, 0);
      }
    }
    if (p >= 1) {
      #pragma unroll
      for (int ks = 0; ks < 16; ++ks) {
        bfrag w = *(const bfrag*)&w2b[ks * 32];
        bfrag u = *(const bfrag*)&u2b[ks * 32];
        bfrag xh = *(const bfrag*)&lA[0][l15][ks * 32 + l4 * 8];
        bfrag xl = *(const bfrag*)&lA[1][l15][ks * 32 + l4 * 8];
        bfrag hh = *(const bfrag*)&lB[0][l15][ks * 32 + l4 * 8];
        bfrag hl = *(const bfrag*)&lB[1][l15][ks * 32 + l4 * 8];
        b0 = __builtin_amdgcn_mfma_f32_16x16x32_bf16(xh, w, b0, 0, 0, 0);
        b1 = __builtin_amdgcn_mfma_f32_16x16x32_bf16(xl, w, b1, 0, 0, 0);
        b2a = __builtin_amdgcn_mfma_f32_16x16x32_bf16(hh, u, b2a, 0, 0, 0);
        b3 = __builtin_amdgcn_mfma_f32_16x16x32_bf16(hl, u, b3, 0, 0, 0);
      }
    }

    if (p < Tq) {                       // epilogue A -> hA(p)
      a0 += a1;
      *(f32x4*)&zt[wv][l15][l4 * 4] = a0;
      __syncthreads();
      f32x4 xg = *(const f32x4*)&XW[(size_t)(p * Bq + bb) * G4H + hidx * 4];
      float zi = zt[wv][4 * jj + 0][bb] + xg[0];
      float zf = zt[wv][4 * jj + 1][bb] + xg[1];
      float zg = zt[wv][4 * jj + 2][bb] + xg[2];
      float zo = zt[wv][4 * jj + 3][bb] + xg[3];
      cAr = sigm(zf) * cAr + sigm(zi) * tanhf(zg);
      float hN = sigm(zo) * tanhf(cAr);
      int hi_ = (int)(unsigned short)f2bf(hN);
      int lo_ = (int)(unsigned short)f2bf(hN - bf2f((short)hi_));
      int hi2 = __shfl_xor(hi_, 1), lo2 = __shfl_xor(lo_, 1);
      if ((jj & 1) == 0) {
        int pi = (bb * Hq + hidx) >> 1;
        u32* dst = hAbuf + (size_t)((p + 1) & 1) * 2 * HPAIR + pi;
        ic_store(dst, (u32)hi_ | ((u32)hi2 << 16));
        ic_store(dst + HPAIR, (u32)lo_ | ((u32)lo2 << 16));
      }
      __syncthreads();                  // zt reuse guard
    }
    if (p >= 1) {                       // epilogue B -> hB(p-1)
      int s = p - 1;
      b0 += b1; b0 += b2a; b0 += b3;
      *(f32x4*)&zt[wv][l15][l4 * 4] = b0;
      __syncthreads();
      float zi = zt[wv][4 * jj + 0][bb] + bdi;
      float zf = zt[wv][4 * jj + 1][bb] + bdf;
      float zg = zt[wv][4 * jj + 2][bb] + bdg;
      float zo = zt[wv][4 * jj + 3][bb] + bdo;
      cBr = sigm(zf) * cBr + sigm(zi) * tanhf(zg);
      float hN = sigm(zo) * tanhf(cBr);
      int hi_ = (int)(unsigned short)f2bf(hN);
      int lo_ = (int)(unsigned short)f2bf(hN - bf2f((short)hi_));
      int hi2 = __shfl_xor(hi_, 1), lo2 = __shfl_xor(lo_, 1);
      if ((jj & 1) == 0) {
        int pi = (bb * Hq + hidx) >> 1;
        u32* dst = hBbuf + (size_t)((p + 1) & 1) * 2 * HPAIR + pi;
        ic_store(dst, (u32)hi_ | ((u32)hi2 << 16));
        ic_store(dst + HPAIR, (u32)lo_ | ((u32)lo2 << 16));
      }
      hBseq[(size_t)(s * Bq + bb) * Hq + hidx] = hN;
      decb[((size_t)bb * Tq + s) * (2 * Hq) + hidx] = hN;
    }
    icbar(flags, (u32)(p + 2));
  }
}

// ---------------- batched attention over full seq2 (one block per (b,t))
__global__ __launch_bounds__(256) void k_attn(const float* __restrict__ seq2,
                                              const float* __restrict__ hBseq,
                                              float* __restrict__ dec) {
  int blk = blockIdx.x;
  int b = blk >> 7, t = blk & 127;
  __shared__ float q[Hq];
  __shared__ float part[256];
  __shared__ float p[Tq];
  int tid = threadIdx.x;
  const float* qsrc = hBseq + (size_t)(t * Bq + b) * Hq;
  q[tid] = qsrc[tid]; q[tid + 256] = qsrc[tid + 256];
  __syncthreads();
  {
    int s = tid >> 1, half = tid & 1;
    const float* row = seq2 + (size_t)(s * Bq + b) * Hq + half * 256;
    const float* qh = q + half * 256;
    float a = 0.0f;
    for (int k = 0; k < 256; k += 4) {
      f32x4 r4 = *(const f32x4*)(row + k);
      f32x4 q4 = *(const f32x4*)(qh + k);
      a += r4[0] * q4[0] + r4[1] * q4[1] + r4[2] * q4[2] + r4[3] * q4[3];
    }
    part[tid] = a;
  }
  __syncthreads();
  if (tid < 64) {
    float v0 = part[2 * tid] + part[2 * tid + 1];
    float v1 = part[2 * (tid + 64)] + part[2 * (tid + 64) + 1];
    float mx = fmaxf(v0, v1);
    for (int off = 32; off; off >>= 1) mx = fmaxf(mx, __shfl_xor(mx, off));
    float e0 = __expf(v0 - mx), e1 = __expf(v1 - mx);
    float sm = e0 + e1;
    for (int off = 32; off; off >>= 1) sm += __shfl_xor(sm, off);
    float inv = 1.0f / sm;
    p[tid] = e0 * inv; p[tid + 64] = e1 * inv;
  }
  __syncthreads();
  float c0 = 0.0f, c1 = 0.0f;
  for (int s = 0; s < Tq; ++s) {
    float ps = p[s];
    const float* row = seq2 + (size_t)(s * Bq + b) * Hq;
    c0 += ps * row[tid];
    c1 += ps * row[tid + 256];
  }
  float* drow = dec + (size_t)(b * Tq + t) * (2 * Hq) + Hq;
  drow[tid] = c0; drow[tid + 256] = c1;
}

// ---------------- row softmax over VO=32001 (in-place on d_out)
__global__ __launch_bounds__(256) void k_softmax(float* __restrict__ L) {
  int row = blockIdx.x;
  float* p = L + (size_t)row * VO;
  int tid = threadIdx.x;
  float m = -3.0e38f, s = 0.0f;
  for (int i = tid; i < VO; i += 256) {
    float v = p[i];
    float mn = fmaxf(m, v);
    s = s * __expf(m - mn) + __expf(v - mn);
    m = mn;
  }
  __shared__ float sm[256], ss[256];
  sm[tid] = m; ss[tid] = s;
  __syncthreads();
  for (int off = 128; off; off >>= 1) {
    if (tid < off) {
      float m2 = sm[tid + off], s2 = ss[tid + off];
      float mn = fmaxf(sm[tid], m2);
      ss[tid] = ss[tid] * __expf(sm[tid] - mn) + s2 * __expf(m2 - mn);
      sm[tid] = mn;
    }
    __syncthreads();
  }
  float M = sm[0], IS = 1.0f / ss[0];
  for (int i = tid; i < VO; i += 256) {
    p[i] = __expf(p[i] - M) * IS;
  }
}

// =============================================================================
extern "C" void kernel_launch(void* const* d_in, const int* in_sizes, int n_in,
                              void* d_out, int out_size, void* d_ws, size_t ws_size,
                              hipStream_t stream) {
  const int*   tokens = (const int*)d_in[0];
  const float* emb    = (const float*)d_in[1];
  const float* W1     = (const float*)d_in[2];
  const float* U1     = (const float*)d_in[3];
  const float* b1     = (const float*)d_in[4];
  const float* W2     = (const float*)d_in[5];
  const float* U2     = (const float*)d_in[6];
  const float* b2     = (const float*)d_in[7];
  const float* Wd1    = (const float*)d_in[8];
  const float* Ud1    = (const float*)d_in[9];
  const float* bd1    = (const float*)d_in[10];
  const float* Wd2    = (const float*)d_in[11];
  const float* Ud2    = (const float*)d_in[12];
  const float* bd2    = (const float*)d_in[13];
  const float* Wo     = (const float*)d_in[14];
  const float* bo     = (const float*)d_in[15];
  float* out = (float*)d_out;

  size_t off = 0;
  char* base = (char*)d_ws;
  auto alloc = [&](size_t bytes) -> void* {
    void* p = base + off;
    off += (bytes + 255) & ~(size_t)255;
    return p;
  };
  u32*   flags   = (u32*)alloc(3 * 4096);
  short* x_bf    = (short*)alloc((size_t)MR * Dq * 2);
  short* W1T     = (short*)alloc((size_t)G4H * Dq * 2);
  short* W2T     = (short*)alloc((size_t)G4H * Hq * 2);
  short* Wd1T    = (short*)alloc((size_t)G4H * Hq * 2);
  short* WoT     = (short*)alloc((size_t)NPAD * (2 * Hq) * 2);
  short* U1T     = (short*)alloc((size_t)G4H * Hq * 2);
  short* U2T     = (short*)alloc((size_t)G4H * Hq * 2);
  short* Ud1T    = (short*)alloc((size_t)G4H * Hq * 2);
  short* Ud2T    = (short*)alloc((size_t)G4H * Hq * 2);
  short* Wd2T    = (short*)alloc((size_t)G4H * Hq * 2);
  float* XW      = (float*)alloc((size_t)MR * G4H * 4);       // reused x3
  short* seq1_bf = (short*)alloc((size_t)MR * Hq * 2);
  short* seq2_bf = (short*)alloc((size_t)MR * Hq * 2);
  float* seq2    = (float*)alloc((size_t)MR * Hq * 4);
  float* hBseq   = (float*)alloc((size_t)MR * Hq * 4);
  float* dec     = (float*)alloc((size_t)MR * 2 * Hq * 4);
  short* dec_bf  = (short*)alloc((size_t)MR * 2 * Hq * 2);
  u32*   h1buf   = (u32*)alloc((size_t)4 * HPAIR * 4);
  u32*   h2buf   = (u32*)alloc((size_t)4 * HPAIR * 4);
  u32*   hAbuf   = (u32*)alloc((size_t)4 * HPAIR * 4);
  u32*   hBbuf   = (u32*)alloc((size_t)4 * HPAIR * 4);
  float* h1f = (float*)alloc(BH * 4);
  float* c1f = (float*)alloc(BH * 4);
  float* h2f = (float*)alloc(BH * 4);
  float* c2f = (float*)alloc(BH * 4);
  u32* flags0 = flags;
  u32* flags1 = flags + 1024;
  u32* flags2 = flags + 2048;
  (void)ws_size; (void)in_sizes; (void)n_in; (void)out_size;

  hipMemsetAsync(flags, 0, 3 * 4096, stream);

  // weight transposes + bf16 conversion (+ gate-interleave perm on recurrent mats)
  k_transcvt<<<dim3(G4H / 32, Dq / 32), 256, 0, stream>>>(W1, W1T, Dq, G4H, 1);
  k_transcvt<<<dim3(G4H / 32, Hq / 32), 256, 0, stream>>>(W2, W2T, Hq, G4H, 1);
  k_transcvt<<<dim3(G4H / 32, Hq / 32), 256, 0, stream>>>(Wd1, Wd1T, Hq, G4H, 1);
  k_transcvt<<<dim3(G4H / 32, Hq / 32), 256, 0, stream>>>(U1, U1T, Hq, G4H, 1);
  k_transcvt<<<dim3(G4H / 32, Hq / 32), 256, 0, stream>>>(U2, U2T, Hq, G4H, 1);
  k_transcvt<<<dim3(G4H / 32, Hq / 32), 256, 0, stream>>>(Ud1, Ud1T, Hq, G4H, 1);
  k_transcvt<<<dim3(G4H / 32, Hq / 32), 256, 0, stream>>>(Ud2, Ud2T, Hq, G4H, 1);
  k_transcvt<<<dim3(G4H / 32, Hq / 32), 256, 0, stream>>>(Wd2, Wd2T, Hq, G4H, 1);
  k_transcvt<<<dim3(NPAD / 32, (2 * Hq) / 32), 256, 0, stream>>>(Wo, WoT, 2 * Hq, VO, 0);

  k_gather<<<MR, 256, 0, stream>>>(tokens, emb, x_bf);

  // encoder layer 1
  k_gemm<<<dim3(G4H / 128, MR / 128), 256, 0, stream>>>(x_bf, W1T, XW, b1, MR, G4H, Dq, G4H, 1);
  k_rec<<<NBLK, 256, 0, stream>>>(XW, U1T, nullptr, nullptr, h1buf, h1f, c1f, seq1_bf, nullptr, flags0);

  // encoder layer 2 (init from layer-1 finals)
  k_gemm<<<dim3(G4H / 128, MR / 128), 256, 0, stream>>>(seq1_bf, W2T, XW, b2, MR, G4H, Hq, G4H, 1);
  k_rec<<<NBLK, 256, 0, stream>>>(XW, U2T, h1f, c1f, h2buf, h2f, c2f, seq2_bf, seq2, flags1);

  // decoder (cells A,B skewed)
  k_gemm<<<dim3(G4H / 128, MR / 128), 256, 0, stream>>>(seq2_bf, Wd1T, XW, bd1, MR, G4H, Hq, G4H, 1);
  k_dec2<<<NBLK, 256, 0, stream>>>(XW, Ud1T, Wd2T, Ud2T, bd2, h1f, c1f, h2f, c2f,
                                   hAbuf, hBbuf, hBseq, dec, flags2);

  // attention + logits + softmax
  k_attn<<<MR, 256, 0, stream>>>(seq2, hBseq, dec);
  k_cvt<<<(MR * 2 * Hq) / 1024, 256, 0, stream>>>(dec, dec_bf, MR * 2 * Hq);
  k_gemm<<<dim3(NPAD / 128, MR / 128), 256, 0, stream>>>(dec_bf, WoT, out, bo, MR, VO, 2 * Hq, VO, 0);
  k_softmax<<<MR, 256, 0, stream>>>(out);
}

// Round 4
// 2813.737 us; speedup vs baseline: 1.3807x; 1.3807x over previous
//
#include <hip/hip_runtime.h>
#include <hip/hip_bf16.h>
#include <math.h>

// Model dims
#define Bq   16
#define Tq   128
#define Hq   512
#define Dq   256
#define G4H  2048            // 4*H
#define MR   2048            // B*T rows
#define VO   32001           // VOUT+1
#define NPAD 32128           // VO padded to multiple of 128
#define NBLK 32              // persistent blocks for recurrence
#define BH   (Bq * Hq)       // 8192
#define HP64 4096            // u64 pairs per parity plane (hi+lo packed)

typedef unsigned int u32;
typedef unsigned long long u64;
typedef __attribute__((ext_vector_type(4))) float f32x4;
typedef __attribute__((ext_vector_type(8))) short bfrag;   // 8 x bf16 (4 VGPRs)
typedef __attribute__((ext_vector_type(4))) float facc;    // mfma accumulator

__device__ __forceinline__ float bf2f(short s) {
  union { unsigned u; float f; } v; v.u = ((unsigned)(unsigned short)s) << 16; return v.f;
}
__device__ __forceinline__ short f2bf(float f) {
  union { float f; unsigned u; } v; v.f = f;
  unsigned r = (v.u + 0x7fffu + ((v.u >> 16) & 1u)) >> 16;
  return (short)r;
}
__device__ __forceinline__ float sigm(float x) { return 1.0f / (1.0f + expf(-x)); }

__device__ __forceinline__ void ic_store64(u64* p, u64 v) {
  __hip_atomic_store(p, v, __ATOMIC_RELAXED, __HIP_MEMORY_SCOPE_AGENT);
}
__device__ __forceinline__ u64 ic_load64(const u64* p) {
  return __hip_atomic_load(p, __ATOMIC_RELAXED, __HIP_MEMORY_SCOPE_AGENT);
}

// ---- split barrier: signal (per-wave vmcnt drain -> block sync -> flag), wait (poll)
__device__ __forceinline__ void barsig(u32* flags, u32 ph) {
  asm volatile("s_waitcnt vmcnt(0)" ::: "memory");   // each wave drains ITS stores
  __syncthreads();                                   // all waves drained
  if (threadIdx.x == 0)
    __hip_atomic_store(&flags[blockIdx.x * 32], ph, __ATOMIC_RELAXED, __HIP_MEMORY_SCOPE_AGENT);
}
__device__ __forceinline__ void barwait(u32* flags, u32 ph) {
  if (threadIdx.x < NBLK) {
    while (__hip_atomic_load(&flags[threadIdx.x * 32], __ATOMIC_RELAXED, __HIP_MEMORY_SCOPE_AGENT) < ph)
      __builtin_amdgcn_s_sleep(1);
  }
  __syncthreads();
}

// ---- XOR-swizzled LDS addressing for a [16][520]-short plane (row stride 1040B)
__device__ __forceinline__ void* swz(void* plane, int row, int byteoff) {
  return (void*)((char*)plane + row * 1040 + (byteoff ^ ((row & 7) << 4)));
}

// ---------------- transpose + f32->bf16 (+ optional gate-interleave col perm)
__global__ __launch_bounds__(256) void k_transcvt(const float* __restrict__ in,
                                                  short* __restrict__ out,
                                                  int R, int N, int perm) {
  __shared__ float tile[32][33];
  int nb = blockIdx.x * 32, rb = blockIdx.y * 32;
  int tx = threadIdx.x & 31, ty = threadIdx.x >> 5;
  for (int i = 0; i < 4; ++i) {
    int r = rb + ty + i * 8;
    int n = nb + tx;
    tile[ty + i * 8][tx] = (n < N) ? in[(size_t)r * N + n] : 0.0f;
  }
  __syncthreads();
  for (int i = 0; i < 4; ++i) {
    int n = nb + ty + i * 8;
    int orow = perm ? (((n & 511) << 2) | (n >> 9)) : n;
    out[(size_t)orow * R + rb + tx] = f2bf(tile[tx][ty + i * 8]);
  }
}

// ---------------- flat f32 -> bf16
__global__ __launch_bounds__(256) void k_cvt(const float* __restrict__ in,
                                             short* __restrict__ out, int n) {
  int i = (blockIdx.x * 256 + threadIdx.x) * 4;
  if (i + 3 < n) {
    f32x4 v = *(const f32x4*)(in + i);
    short4 o;
    o.x = f2bf(v[0]); o.y = f2bf(v[1]); o.z = f2bf(v[2]); o.w = f2bf(v[3]);
    *(short4*)(out + i) = o;
  }
}

// ---------------- embedding gather -> x_bf [T*B, D] bf16
__global__ __launch_bounds__(256) void k_gather(const int* __restrict__ tokens,
                                                const float* __restrict__ emb,
                                                short* __restrict__ xbf) {
  int row = blockIdx.x;                 // t*16+b
  int t = row >> 4, b = row & 15;
  int tok = tokens[b * Tq + t];
  xbf[(size_t)row * Dq + threadIdx.x] = f2bf(emb[(size_t)tok * Dq + threadIdx.x]);
}

// ---------------- bf16 MFMA GEMM: C[M,ldc] = A[M,K] @ BT[Npad,K]^T + bias
__global__ __launch_bounds__(256) void k_gemm(const short* __restrict__ A,
                                              const short* __restrict__ BT,
                                              float* __restrict__ C,
                                              const float* __restrict__ bias,
                                              int M, int Nreal, int K, int ldc,
                                              int permb) {
  __shared__ short lA[128 * 64];
  __shared__ short lB[128 * 64];
  const int tid = threadIdx.x;
  const int wave = tid >> 6, lane = tid & 63;
  const int l15 = lane & 15, l4 = lane >> 4;
  const int m0 = blockIdx.y * 128, n0 = blockIdx.x * 128;
  const int wm = (wave >> 1) * 64, wn = (wave & 1) * 64;
  facc acc[4][4] = {};

  for (int k0 = 0; k0 < K; k0 += 64) {
    __syncthreads();
    for (int i = 0; i < 4; ++i) {
      int c = i * 256 + wave * 64 + lane;
      int r = c >> 3, q = c & 7;
      int qs = q ^ (r & 7);
      const short* ga = A + (size_t)(m0 + r) * K + k0 + qs * 8;
      const short* gb = BT + (size_t)(n0 + r) * K + k0 + qs * 8;
      short* la = lA + (size_t)(i * 256 + wave * 64) * 8;
      short* lb = lB + (size_t)(i * 256 + wave * 64) * 8;
      __builtin_amdgcn_global_load_lds((const __attribute__((address_space(1))) u32*)ga,
                                       (__attribute__((address_space(3))) u32*)la, 16, 0, 0);
      __builtin_amdgcn_global_load_lds((const __attribute__((address_space(1))) u32*)gb,
                                       (__attribute__((address_space(3))) u32*)lb, 16, 0, 0);
    }
    __syncthreads();
    for (int ks = 0; ks < 2; ++ks) {
      bfrag a[4], b[4];
      for (int mi = 0; mi < 4; ++mi) {
        int r = wm + mi * 16 + l15;
        int qs = (ks * 4 + l4) ^ (r & 7);
        a[mi] = *(const bfrag*)&lA[r * 64 + qs * 8];
      }
      for (int ni = 0; ni < 4; ++ni) {
        int r = wn + ni * 16 + l15;
        int qs = (ks * 4 + l4) ^ (r & 7);
        b[ni] = *(const bfrag*)&lB[r * 64 + qs * 8];
      }
      for (int mi = 0; mi < 4; ++mi)
        for (int ni = 0; ni < 4; ++ni)
          acc[mi][ni] = __builtin_amdgcn_mfma_f32_16x16x32_bf16(a[mi], b[ni], acc[mi][ni], 0, 0, 0);
    }
  }
  for (int ni = 0; ni < 4; ++ni) {
    int col = n0 + wn + ni * 16 + l15;
    if (col >= Nreal) continue;
    int bcol = permb ? (((col & 3) << 9) | (col >> 2)) : col;
    float bs = bias ? bias[bcol] : 0.0f;
    for (int mi = 0; mi < 4; ++mi) {
      int rb = m0 + wm + mi * 16 + l4 * 4;
      facc v = acc[mi][ni];
      C[(size_t)(rb + 0) * ldc + col] = v[0] + bs;
      C[(size_t)(rb + 1) * ldc + col] = v[1] + bs;
      C[(size_t)(rb + 2) * ldc + col] = v[2] + bs;
      C[(size_t)(rb + 3) * ldc + col] = v[3] + bs;
    }
  }
}

// h exchange buffer: u64 hbuf[2 parity][HP64]; element pi=(bb*512+col)/2 packs
// (hi_even|hi_odd<<16) | (lo_even|lo_odd<<16)<<32.

// ---------------- single-cell LSTM recurrence (persistent, NBLK x 512, U in VGPRs)
__global__ __launch_bounds__(512) void k_rec(const float* __restrict__ XW,
                                             const short* __restrict__ UT,
                                             const float* __restrict__ hinit,
                                             const float* __restrict__ cinit,
                                             u64* __restrict__ hbuf,
                                             float* __restrict__ hfin,
                                             float* __restrict__ cfin,
                                             short* __restrict__ seq_bf,
                                             float* __restrict__ seq_f32,
                                             u32* flags, int dry) {
  __shared__ short lh[2][16][520];
  __shared__ float zt[8][16][20];
  const int tid = threadIdx.x;
  const int wv = tid >> 6, lane = tid & 63;
  const int l15 = lane & 15, l4 = lane >> 4;
  const int kh = wv >> 2;                       // k-half 0/1
  const int gw = blockIdx.x * 4 + (wv & 3);     // 0..127
  const int bb = lane >> 2, jj = lane & 3;
  const int hidx = gw * 4 + jj;

  bfrag ur[8];                                  // U slice in VGPRs (32 VGPRs)
  {
    const short* ub = UT + (size_t)(gw * 16 + l15) * Hq + kh * 256 + l4 * 8;
    #pragma unroll
    for (int ks = 0; ks < 8; ++ks) ur[ks] = *(const bfrag*)&ub[ks * 32];
  }
  float c = 0.0f;
  if (wv < 4) {
    c = cinit ? cinit[bb * Hq + hidx] : 0.0f;
    float hv = hinit ? hinit[bb * Hq + hidx] : 0.0f;
    int hi_ = (int)(unsigned short)f2bf(hv);
    int lo_ = (int)(unsigned short)f2bf(hv - bf2f((short)hi_));
    int hi2 = __shfl_xor(hi_, 1), lo2 = __shfl_xor(lo_, 1);
    if ((jj & 1) == 0) {
      u64 v = (u64)((u32)hi_ | ((u32)hi2 << 16)) | ((u64)((u32)lo_ | ((u32)lo2 << 16)) << 32);
      ic_store64(&hbuf[(bb * Hq + hidx) >> 1], v);
    }
  }
  u32 ph = 0;
  for (int d = 0; d < dry; ++d) { ++ph; barsig(flags, ph); barwait(flags, ph); }  // barrier probe
  ++ph; barsig(flags, ph); barwait(flags, ph);

  for (int s = 0; s < Tq; ++s) {
    f32x4 xg = {};
    if (wv < 4) xg = *(const f32x4*)&XW[(size_t)(s * Bq + bb) * G4H + hidx * 4];  // prefetch
    const u64* hsrc = hbuf + (size_t)(s & 1) * HP64;
    #pragma unroll
    for (int it = 0; it < 8; ++it) {
      int i = it * 512 + tid;
      u64 v = ic_load64(&hsrc[i]);
      int b = i >> 8, bo = (i & 255) * 4;
      *(u32*)swz(&lh[0][0][0], b, bo) = (u32)v;
      *(u32*)swz(&lh[1][0][0], b, bo) = (u32)(v >> 32);
    }
    __syncthreads();
    facc a0 = {}, a1 = {};
    #pragma unroll
    for (int ks = 0; ks < 8; ++ks) {
      int bo = kh * 512 + ks * 64 + l4 * 16;
      bfrag ah = *(const bfrag*)swz(&lh[0][0][0], l15, bo);
      bfrag al = *(const bfrag*)swz(&lh[1][0][0], l15, bo);
      a0 = __builtin_amdgcn_mfma_f32_16x16x32_bf16(ah, ur[ks], a0, 0, 0, 0);
      a1 = __builtin_amdgcn_mfma_f32_16x16x32_bf16(al, ur[ks], a1, 0, 0, 0);
    }
    a0 += a1;
    *(f32x4*)&zt[wv][l15][l4 * 4] = a0;
    __syncthreads();
    float hN = 0.0f; int hi_ = 0;
    if (wv < 4) {
      float zi = zt[wv][4 * jj + 0][bb] + zt[wv + 4][4 * jj + 0][bb] + xg[0];
      float zf = zt[wv][4 * jj + 1][bb] + zt[wv + 4][4 * jj + 1][bb] + xg[1];
      float zg = zt[wv][4 * jj + 2][bb] + zt[wv + 4][4 * jj + 2][bb] + xg[2];
      float zo = zt[wv][4 * jj + 3][bb] + zt[wv + 4][4 * jj + 3][bb] + xg[3];
      c = sigm(zf) * c + sigm(zi) * tanhf(zg);
      hN = sigm(zo) * tanhf(c);
      hi_ = (int)(unsigned short)f2bf(hN);
      int lo_ = (int)(unsigned short)f2bf(hN - bf2f((short)hi_));
      int hi2 = __shfl_xor(hi_, 1), lo2 = __shfl_xor(lo_, 1);
      if (s < Tq - 1 && (jj & 1) == 0) {
        u64 v = (u64)((u32)hi_ | ((u32)hi2 << 16)) | ((u64)((u32)lo_ | ((u32)lo2 << 16)) << 32);
        ic_store64(&hbuf[(size_t)((s + 1) & 1) * HP64 + ((bb * Hq + hidx) >> 1)], v);
      }
    }
    if (s < Tq - 1) {
      ++ph; barsig(flags, ph);
      if (wv < 4) {                       // trailing stores drain during next poll
        seq_bf[(size_t)(s * Bq + bb) * Hq + hidx] = (short)hi_;
        if (seq_f32) seq_f32[(size_t)(s * Bq + bb) * Hq + hidx] = hN;
      }
      barwait(flags, ph);
    } else if (wv < 4) {
      seq_bf[(size_t)(s * Bq + bb) * Hq + hidx] = (short)hi_;
      if (seq_f32) seq_f32[(size_t)(s * Bq + bb) * Hq + hidx] = hN;
      hfin[bb * Hq + hidx] = hN;
      cfin[bb * Hq + hidx] = c;
    }
  }
}

// ---------------- decoder: cells A and B skewed; epilogues concurrent on wave halves
__global__ __launch_bounds__(512) void k_dec2(const float* __restrict__ XW,
                                              const short* __restrict__ U1T,   // Ud1'
                                              const short* __restrict__ W2T,   // Wd2'
                                              const short* __restrict__ U2T,   // Ud2'
                                              const float* __restrict__ bd2,
                                              const float* __restrict__ h1f, const float* __restrict__ c1f,
                                              const float* __restrict__ h2f, const float* __restrict__ c2f,
                                              u64* __restrict__ hAbuf, u64* __restrict__ hBbuf,
                                              float* __restrict__ hBseq, float* __restrict__ decb,
                                              u32* flags) {
  __shared__ short lA[2][16][520];
  __shared__ short lB[2][16][520];
  __shared__ float ztA[8][16][20];
  __shared__ float ztB[8][16][20];
  const int tid = threadIdx.x;
  const int wv = tid >> 6, lane = tid & 63;
  const int l15 = lane & 15, l4 = lane >> 4;
  const int kh = wv >> 2;
  const int gw = blockIdx.x * 4 + (wv & 3);
  const int bb = lane >> 2, jj = lane & 3;
  const int hidx = gw * 4 + jj;

  bfrag u1r[8], w2r[8], u2r[8];                 // 96 VGPRs of weights
  {
    size_t ro = (size_t)(gw * 16 + l15) * Hq + kh * 256 + l4 * 8;
    #pragma unroll
    for (int ks = 0; ks < 8; ++ks) {
      u1r[ks] = *(const bfrag*)&U1T[ro + ks * 32];
      w2r[ks] = *(const bfrag*)&W2T[ro + ks * 32];
      u2r[ks] = *(const bfrag*)&U2T[ro + ks * 32];
    }
  }
  float cc = 0.0f, bdi = 0, bdf = 0, bdg = 0, bdo = 0;
  {
    const float* cf = (wv < 4) ? c1f : c2f;
    const float* hf = (wv < 4) ? h1f : h2f;
    cc = cf[bb * Hq + hidx];
    float hv = hf[bb * Hq + hidx];
    int hi_ = (int)(unsigned short)f2bf(hv);
    int lo_ = (int)(unsigned short)f2bf(hv - bf2f((short)hi_));
    int hi2 = __shfl_xor(hi_, 1), lo2 = __shfl_xor(lo_, 1);
    if ((jj & 1) == 0) {
      u64 v = (u64)((u32)hi_ | ((u32)hi2 << 16)) | ((u64)((u32)lo_ | ((u32)lo2 << 16)) << 32);
      u64* hb = (wv < 4) ? hAbuf : hBbuf;
      int pi = (bb * Hq + hidx) >> 1;
      ic_store64(&hb[pi], v);
      ic_store64(&hb[HP64 + pi], v);
    }
    if (wv >= 4) {
      bdi = bd2[hidx]; bdf = bd2[Hq + hidx];
      bdg = bd2[2 * Hq + hidx]; bdo = bd2[3 * Hq + hidx];
    }
  }
  u32 ph = 1;
  barsig(flags, ph); barwait(flags, ph);

  for (int p = 0; p <= Tq; ++p) {
    f32x4 xg = {};
    if (wv < 4 && p < Tq) xg = *(const f32x4*)&XW[(size_t)(p * Bq + bb) * G4H + hidx * 4];
    const u64* asrc = hAbuf + (size_t)(p & 1) * HP64;
    const u64* bsrc = hBbuf + (size_t)(p & 1) * HP64;
    #pragma unroll
    for (int it = 0; it < 8; ++it) {
      int i = it * 512 + tid;
      u64 va = ic_load64(&asrc[i]);
      u64 vb = ic_load64(&bsrc[i]);
      int b = i >> 8, bo = (i & 255) * 4;
      *(u32*)swz(&lA[0][0][0], b, bo) = (u32)va;
      *(u32*)swz(&lA[1][0][0], b, bo) = (u32)(va >> 32);
      *(u32*)swz(&lB[0][0][0], b, bo) = (u32)vb;
      *(u32*)swz(&lB[1][0][0], b, bo) = (u32)(vb >> 32);
    }
    __syncthreads();

    facc a0 = {}, a1 = {}, b0 = {}, b1 = {}, b2 = {}, b3 = {};
    #pragma unroll
    for (int ks = 0; ks < 8; ++ks) {
      int bo = kh * 512 + ks * 64 + l4 * 16;
      bfrag ah = *(const bfrag*)swz(&lA[0][0][0], l15, bo);
      bfrag al = *(const bfrag*)swz(&lA[1][0][0], l15, bo);
      if (p < Tq) {
        a0 = __builtin_amdgcn_mfma_f32_16x16x32_bf16(ah, u1r[ks], a0, 0, 0, 0);
        a1 = __builtin_amdgcn_mfma_f32_16x16x32_bf16(al, u1r[ks], a1, 0, 0, 0);
      }
      if (p >= 1) {
        bfrag hh = *(const bfrag*)swz(&lB[0][0][0], l15, bo);
        bfrag hl = *(const bfrag*)swz(&lB[1][0][0], l15, bo);
        b0 = __builtin_amdgcn_mfma_f32_16x16x32_bf16(ah, w2r[ks], b0, 0, 0, 0);
        b1 = __builtin_amdgcn_mfma_f32_16x16x32_bf16(al, w2r[ks], b1, 0, 0, 0);
        b2 = __builtin_amdgcn_mfma_f32_16x16x32_bf16(hh, u2r[ks], b2, 0, 0, 0);
        b3 = __builtin_amdgcn_mfma_f32_16x16x32_bf16(hl, u2r[ks], b3, 0, 0, 0);
      }
    }
    if (p < Tq) { a0 += a1; *(f32x4*)&ztA[wv][l15][l4 * 4] = a0; }
    if (p >= 1) { b0 += b1; b0 += b2; b0 += b3; *(f32x4*)&ztB[wv][l15][l4 * 4] = b0; }
    __syncthreads();

    float hNB = 0.0f;
    if (wv < 4 && p < Tq) {               // epilogue A (concurrent with B)
      float zi = ztA[wv][4 * jj + 0][bb] + ztA[wv + 4][4 * jj + 0][bb] + xg[0];
      float zf = ztA[wv][4 * jj + 1][bb] + ztA[wv + 4][4 * jj + 1][bb] + xg[1];
      float zg = ztA[wv][4 * jj + 2][bb] + ztA[wv + 4][4 * jj + 2][bb] + xg[2];
      float zo = ztA[wv][4 * jj + 3][bb] + ztA[wv + 4][4 * jj + 3][bb] + xg[3];
      cc = sigm(zf) * cc + sigm(zi) * tanhf(zg);
      float hN = sigm(zo) * tanhf(cc);
      int hi_ = (int)(unsigned short)f2bf(hN);
      int lo_ = (int)(unsigned short)f2bf(hN - bf2f((short)hi_));
      int hi2 = __shfl_xor(hi_, 1), lo2 = __shfl_xor(lo_, 1);
      if ((jj & 1) == 0) {
        u64 v = (u64)((u32)hi_ | ((u32)hi2 << 16)) | ((u64)((u32)lo_ | ((u32)lo2 << 16)) << 32);
        ic_store64(&hAbuf[(size_t)((p + 1) & 1) * HP64 + ((bb * Hq + hidx) >> 1)], v);
      }
    }
    if (wv >= 4 && p >= 1) {              // epilogue B
      int pw = wv - 4;
      float zi = ztB[pw][4 * jj + 0][bb] + ztB[wv][4 * jj + 0][bb] + bdi;
      float zf = ztB[pw][4 * jj + 1][bb] + ztB[wv][4 * jj + 1][bb] + bdf;
      float zg = ztB[pw][4 * jj + 2][bb] + ztB[wv][4 * jj + 2][bb] + bdg;
      float zo = ztB[pw][4 * jj + 3][bb] + ztB[wv][4 * jj + 3][bb] + bdo;
      cc = sigm(zf) * cc + sigm(zi) * tanhf(zg);
      hNB = sigm(zo) * tanhf(cc);
      int hi_ = (int)(unsigned short)f2bf(hNB);
      int lo_ = (int)(unsigned short)f2bf(hNB - bf2f((short)hi_));
      int hi2 = __shfl_xor(hi_, 1), lo2 = __shfl_xor(lo_, 1);
      if (p < Tq && (jj & 1) == 0) {
        u64 v = (u64)((u32)hi_ | ((u32)hi2 << 16)) | ((u64)((u32)lo_ | ((u32)lo2 << 16)) << 32);
        ic_store64(&hBbuf[(size_t)((p + 1) & 1) * HP64 + ((bb * Hq + hidx) >> 1)], v);
      }
    }
    if (p < Tq) {
      ++ph; barsig(flags, ph);
      if (wv >= 4 && p >= 1) {            // trailing writes drain during next poll
        int s = p - 1;
        hBseq[(size_t)(s * Bq + bb) * Hq + hidx] = hNB;
        decb[((size_t)bb * Tq + s) * (2 * Hq) + hidx] = hNB;
      }
      barwait(flags, ph);
    } else if (wv >= 4) {
      int s = Tq - 1;
      hBseq[(size_t)(s * Bq + bb) * Hq + hidx] = hNB;
      decb[((size_t)bb * Tq + s) * (2 * Hq) + hidx] = hNB;
    }
  }
}

// ---------------- batched attention over full seq2 (one block per (b,t))
__global__ __launch_bounds__(256) void k_attn(const float* __restrict__ seq2,
                                              const float* __restrict__ hBseq,
                                              float* __restrict__ dec) {
  int blk = blockIdx.x;
  int b = blk >> 7, t = blk & 127;
  __shared__ float q[Hq];
  __shared__ float part[256];
  __shared__ float p[Tq];
  int tid = threadIdx.x;
  const float* qsrc = hBseq + (size_t)(t * Bq + b) * Hq;
  q[tid] = qsrc[tid]; q[tid + 256] = qsrc[tid + 256];
  __syncthreads();
  {
    int s = tid >> 1, half = tid & 1;
    const float* row = seq2 + (size_t)(s * Bq + b) * Hq + half * 256;
    const float* qh = q + half * 256;
    float a = 0.0f;
    for (int k = 0; k < 256; k += 4) {
      f32x4 r4 = *(const f32x4*)(row + k);
      f32x4 q4 = *(const f32x4*)(qh + k);
      a += r4[0] * q4[0] + r4[1] * q4[1] + r4[2] * q4[2] + r4[3] * q4[3];
    }
    part[tid] = a;
  }
  __syncthreads();
  if (tid < 64) {
    float v0 = part[2 * tid] + part[2 * tid + 1];
    float v1 = part[2 * (tid + 64)] + part[2 * (tid + 64) + 1];
    float mx = fmaxf(v0, v1);
    for (int off = 32; off; off >>= 1) mx = fmaxf(mx, __shfl_xor(mx, off));
    float e0 = __expf(v0 - mx), e1 = __expf(v1 - mx);
    float sm = e0 + e1;
    for (int off = 32; off; off >>= 1) sm += __shfl_xor(sm, off);
    float inv = 1.0f / sm;
    p[tid] = e0 * inv; p[tid + 64] = e1 * inv;
  }
  __syncthreads();
  float c0 = 0.0f, c1 = 0.0f;
  for (int s = 0; s < Tq; ++s) {
    float ps = p[s];
    const float* row = seq2 + (size_t)(s * Bq + b) * Hq;
    c0 += ps * row[tid];
    c1 += ps * row[tid + 256];
  }
  float* drow = dec + (size_t)(b * Tq + t) * (2 * Hq) + Hq;
  drow[tid] = c0; drow[tid + 256] = c1;
}

// ---------------- row softmax over VO=32001 (in-place on d_out)
__global__ __launch_bounds__(256) void k_softmax(float* __restrict__ L) {
  int row = blockIdx.x;
  float* p = L + (size_t)row * VO;
  int tid = threadIdx.x;
  float m = -3.0e38f, s = 0.0f;
  for (int i = tid; i < VO; i += 256) {
    float v = p[i];
    float mn = fmaxf(m, v);
    s = s * __expf(m - mn) + __expf(v - mn);
    m = mn;
  }
  __shared__ float sm[256], ss[256];
  sm[tid] = m; ss[tid] = s;
  __syncthreads();
  for (int off = 128; off; off >>= 1) {
    if (tid < off) {
      float m2 = sm[tid + off], s2 = ss[tid + off];
      float mn = fmaxf(sm[tid], m2);
      ss[tid] = ss[tid] * __expf(sm[tid] - mn) + s2 * __expf(m2 - mn);
      sm[tid] = mn;
    }
    __syncthreads();
  }
  float M = sm[0], IS = 1.0f / ss[0];
  for (int i = tid; i < VO; i += 256) {
    p[i] = __expf(p[i] - M) * IS;
  }
}

// =============================================================================
extern "C" void kernel_launch(void* const* d_in, const int* in_sizes, int n_in,
                              void* d_out, int out_size, void* d_ws, size_t ws_size,
                              hipStream_t stream) {
  const int*   tokens = (const int*)d_in[0];
  const float* emb    = (const float*)d_in[1];
  const float* W1     = (const float*)d_in[2];
  const float* U1     = (const float*)d_in[3];
  const float* b1     = (const float*)d_in[4];
  const float* W2     = (const float*)d_in[5];
  const float* U2     = (const float*)d_in[6];
  const float* b2     = (const float*)d_in[7];
  const float* Wd1    = (const float*)d_in[8];
  const float* Ud1    = (const float*)d_in[9];
  const float* bd1    = (const float*)d_in[10];
  const float* Wd2    = (const float*)d_in[11];
  const float* Ud2    = (const float*)d_in[12];
  const float* bd2    = (const float*)d_in[13];
  const float* Wo     = (const float*)d_in[14];
  const float* bo     = (const float*)d_in[15];
  float* out = (float*)d_out;

  size_t off = 0;
  char* base = (char*)d_ws;
  auto alloc = [&](size_t bytes) -> void* {
    void* p = base + off;
    off += (bytes + 255) & ~(size_t)255;
    return p;
  };
  u32*   flags   = (u32*)alloc(3 * 4096);
  short* x_bf    = (short*)alloc((size_t)MR * Dq * 2);
  short* W1T     = (short*)alloc((size_t)G4H * Dq * 2);
  short* W2T     = (short*)alloc((size_t)G4H * Hq * 2);
  short* Wd1T    = (short*)alloc((size_t)G4H * Hq * 2);
  short* WoT     = (short*)alloc((size_t)NPAD * (2 * Hq) * 2);
  short* U1T     = (short*)alloc((size_t)G4H * Hq * 2);
  short* U2T     = (short*)alloc((size_t)G4H * Hq * 2);
  short* Ud1T    = (short*)alloc((size_t)G4H * Hq * 2);
  short* Ud2T    = (short*)alloc((size_t)G4H * Hq * 2);
  short* Wd2T    = (short*)alloc((size_t)G4H * Hq * 2);
  float* XW      = (float*)alloc((size_t)MR * G4H * 4);       // reused x3
  short* seq1_bf = (short*)alloc((size_t)MR * Hq * 2);
  short* seq2_bf = (short*)alloc((size_t)MR * Hq * 2);
  float* seq2    = (float*)alloc((size_t)MR * Hq * 4);
  float* hBseq   = (float*)alloc((size_t)MR * Hq * 4);
  float* dec     = (float*)alloc((size_t)MR * 2 * Hq * 4);
  short* dec_bf  = (short*)alloc((size_t)MR * 2 * Hq * 2);
  u64*   h1buf   = (u64*)alloc((size_t)2 * HP64 * 8);
  u64*   h2buf   = (u64*)alloc((size_t)2 * HP64 * 8);
  u64*   hAbuf   = (u64*)alloc((size_t)2 * HP64 * 8);
  u64*   hBbuf   = (u64*)alloc((size_t)2 * HP64 * 8);
  float* h1f = (float*)alloc(BH * 4);
  float* c1f = (float*)alloc(BH * 4);
  float* h2f = (float*)alloc(BH * 4);
  float* c2f = (float*)alloc(BH * 4);
  u32* flags0 = flags;
  u32* flags1 = flags + 1024;
  u32* flags2 = flags + 2048;
  (void)ws_size; (void)in_sizes; (void)n_in; (void)out_size;

  hipMemsetAsync(flags, 0, 3 * 4096, stream);

  // weight transposes + bf16 conversion (+ gate-interleave perm on recurrent mats)
  k_transcvt<<<dim3(G4H / 32, Dq / 32), 256, 0, stream>>>(W1, W1T, Dq, G4H, 1);
  k_transcvt<<<dim3(G4H / 32, Hq / 32), 256, 0, stream>>>(W2, W2T, Hq, G4H, 1);
  k_transcvt<<<dim3(G4H / 32, Hq / 32), 256, 0, stream>>>(Wd1, Wd1T, Hq, G4H, 1);
  k_transcvt<<<dim3(G4H / 32, Hq / 32), 256, 0, stream>>>(U1, U1T, Hq, G4H, 1);
  k_transcvt<<<dim3(G4H / 32, Hq / 32), 256, 0, stream>>>(U2, U2T, Hq, G4H, 1);
  k_transcvt<<<dim3(G4H / 32, Hq / 32), 256, 0, stream>>>(Ud1, Ud1T, Hq, G4H, 1);
  k_transcvt<<<dim3(G4H / 32, Hq / 32), 256, 0, stream>>>(Ud2, Ud2T, Hq, G4H, 1);
  k_transcvt<<<dim3(G4H / 32, Hq / 32), 256, 0, stream>>>(Wd2, Wd2T, Hq, G4H, 1);
  k_transcvt<<<dim3(NPAD / 32, (2 * Hq) / 32), 256, 0, stream>>>(Wo, WoT, 2 * Hq, VO, 0);

  k_gather<<<MR, 256, 0, stream>>>(tokens, emb, x_bf);

  // encoder layer 1 (dry=32: pure-barrier probe for (enc1-enc2)/32 timing)
  k_gemm<<<dim3(G4H / 128, MR / 128), 256, 0, stream>>>(x_bf, W1T, XW, b1, MR, G4H, Dq, G4H, 1);
  k_rec<<<NBLK, 512, 0, stream>>>(XW, U1T, nullptr, nullptr, h1buf, h1f, c1f, seq1_bf, nullptr, flags0, 32);

  // encoder layer 2 (init from layer-1 finals)
  k_gemm<<<dim3(G4H / 128, MR / 128), 256, 0, stream>>>(seq1_bf, W2T, XW, b2, MR, G4H, Hq, G4H, 1);
  k_rec<<<NBLK, 512, 0, stream>>>(XW, U2T, h1f, c1f, h2buf, h2f, c2f, seq2_bf, seq2, flags1, 0);

  // decoder (cells A,B skewed)
  k_gemm<<<dim3(G4H / 128, MR / 128), 256, 0, stream>>>(seq2_bf, Wd1T, XW, bd1, MR, G4H, Hq, G4H, 1);
  k_dec2<<<NBLK, 512, 0, stream>>>(XW, Ud1T, Wd2T, Ud2T, bd2, h1f, c1f, h2f, c2f,
                                   hAbuf, hBbuf, hBseq, dec, flags2);

  // attention + logits + softmax
  k_attn<<<MR, 256, 0, stream>>>(seq2, hBseq, dec);
  k_cvt<<<(MR * 2 * Hq) / 1024, 256, 0, stream>>>(dec, dec_bf, MR * 2 * Hq);
  k_gemm<<<dim3(NPAD / 128, MR / 128), 256, 0, stream>>>(dec_bf, WoT, out, bo, MR, VO, 2 * Hq, VO, 0);
  k_softmax<<<MR, 256, 0, stream>>>(out);
}

// Round 5
// 2311.245 us; speedup vs baseline: 1.6809x; 1.2174x over previous
//
#include <hip/hip_runtime.h>
#include <hip/hip_bf16.h>
#include <math.h>

// Model dims
#define Bq   16
#define Tq   128
#define Hq   512
#define Dq   256
#define G4H  2048            // 4*H
#define MR   2048            // B*T rows
#define VO   32001           // VOUT+1
#define NPAD 32128           // VO padded to multiple of 128
#define NBLK 32              // persistent blocks for recurrence
#define BH   (Bq * Hq)       // 8192
#define SENTW 0x7FC0u        // bf16 NaN — impossible h value, used as sentinel
#define SENT64 0x7FC07FC07FC07FC0ull

typedef unsigned int u32;
typedef unsigned long long u64;
typedef __attribute__((ext_vector_type(4))) float f32x4;
typedef __attribute__((ext_vector_type(8))) short bfrag;   // 8 x bf16 (4 VGPRs)
typedef __attribute__((ext_vector_type(4))) float facc;    // mfma accumulator

__device__ __forceinline__ float bf2f(short s) {
  union { unsigned u; float f; } v; v.u = ((unsigned)(unsigned short)s) << 16; return v.f;
}
__device__ __forceinline__ short f2bf(float f) {
  union { float f; unsigned u; } v; v.f = f;
  unsigned r = (v.u + 0x7fffu + ((v.u >> 16) & 1u)) >> 16;
  return (short)r;
}
__device__ __forceinline__ float asf(u32 u) {
  union { u32 u; float f; } v; v.u = u; return v.f;
}
__device__ __forceinline__ float sigm(float x) { return 1.0f / (1.0f + expf(-x)); }

__device__ __forceinline__ void ic_store64(u64* p, u64 v) {
  __hip_atomic_store(p, v, __ATOMIC_RELAXED, __HIP_MEMORY_SCOPE_AGENT);
}
__device__ __forceinline__ u64 ic_load64(const u64* p) {
  return __hip_atomic_load(p, __ATOMIC_RELAXED, __HIP_MEMORY_SCOPE_AGENT);
}

// ---- XOR-swizzled LDS addressing for a [16][520]-short plane (row stride 1040B)
__device__ __forceinline__ void* swz(void* plane, int row, int byteoff) {
  return (void*)((char*)plane + row * 1040 + (byteoff ^ ((row & 7) << 4)));
}

// ---------------- sentinel fill (per-launch reset of the dataflow buffers)
__global__ __launch_bounds__(256) void k_fill(u64* __restrict__ p, int n) {
  int i = blockIdx.x * 256 + threadIdx.x;
  if (i < n) p[i] = SENT64;
}

// ---------------- transpose + f32->bf16 (+ optional gate-interleave col perm)
__global__ __launch_bounds__(256) void k_transcvt(const float* __restrict__ in,
                                                  short* __restrict__ out,
                                                  int R, int N, int perm) {
  __shared__ float tile[32][33];
  int nb = blockIdx.x * 32, rb = blockIdx.y * 32;
  int tx = threadIdx.x & 31, ty = threadIdx.x >> 5;
  for (int i = 0; i < 4; ++i) {
    int r = rb + ty + i * 8;
    int n = nb + tx;
    tile[ty + i * 8][tx] = (n < N) ? in[(size_t)r * N + n] : 0.0f;
  }
  __syncthreads();
  for (int i = 0; i < 4; ++i) {
    int n = nb + ty + i * 8;
    int orow = perm ? (((n & 511) << 2) | (n >> 9)) : n;
    out[(size_t)orow * R + rb + tx] = f2bf(tile[tx][ty + i * 8]);
  }
}

// ---------------- embedding gather -> x_bf [T*B, D] bf16
__global__ __launch_bounds__(256) void k_gather(const int* __restrict__ tokens,
                                                const float* __restrict__ emb,
                                                short* __restrict__ xbf) {
  int row = blockIdx.x;                 // t*16+b
  int t = row >> 4, b = row & 15;
  int tok = tokens[b * Tq + t];
  xbf[(size_t)row * Dq + threadIdx.x] = f2bf(emb[(size_t)tok * Dq + threadIdx.x]);
}

// ---------------- bf16 MFMA GEMM: C[M,ldc] = A[M,K] @ BT[Npad,K]^T + bias
__global__ __launch_bounds__(256) void k_gemm(const short* __restrict__ A,
                                              const short* __restrict__ BT,
                                              float* __restrict__ C,
                                              const float* __restrict__ bias,
                                              int M, int Nreal, int K, int ldc,
                                              int permb) {
  __shared__ short lA[128 * 64];
  __shared__ short lB[128 * 64];
  const int tid = threadIdx.x;
  const int wave = tid >> 6, lane = tid & 63;
  const int l15 = lane & 15, l4 = lane >> 4;
  const int m0 = blockIdx.y * 128, n0 = blockIdx.x * 128;
  const int wm = (wave >> 1) * 64, wn = (wave & 1) * 64;
  facc acc[4][4] = {};

  for (int k0 = 0; k0 < K; k0 += 64) {
    __syncthreads();
    for (int i = 0; i < 4; ++i) {
      int c = i * 256 + wave * 64 + lane;
      int r = c >> 3, q = c & 7;
      int qs = q ^ (r & 7);
      const short* ga = A + (size_t)(m0 + r) * K + k0 + qs * 8;
      const short* gb = BT + (size_t)(n0 + r) * K + k0 + qs * 8;
      short* la = lA + (size_t)(i * 256 + wave * 64) * 8;
      short* lb = lB + (size_t)(i * 256 + wave * 64) * 8;
      __builtin_amdgcn_global_load_lds((const __attribute__((address_space(1))) u32*)ga,
                                       (__attribute__((address_space(3))) u32*)la, 16, 0, 0);
      __builtin_amdgcn_global_load_lds((const __attribute__((address_space(1))) u32*)gb,
                                       (__attribute__((address_space(3))) u32*)lb, 16, 0, 0);
    }
    __syncthreads();
    for (int ks = 0; ks < 2; ++ks) {
      bfrag a[4], b[4];
      for (int mi = 0; mi < 4; ++mi) {
        int r = wm + mi * 16 + l15;
        int qs = (ks * 4 + l4) ^ (r & 7);
        a[mi] = *(const bfrag*)&lA[r * 64 + qs * 8];
      }
      for (int ni = 0; ni < 4; ++ni) {
        int r = wn + ni * 16 + l15;
        int qs = (ks * 4 + l4) ^ (r & 7);
        b[ni] = *(const bfrag*)&lB[r * 64 + qs * 8];
      }
      for (int mi = 0; mi < 4; ++mi)
        for (int ni = 0; ni < 4; ++ni)
          acc[mi][ni] = __builtin_amdgcn_mfma_f32_16x16x32_bf16(a[mi], b[ni], acc[mi][ni], 0, 0, 0);
    }
  }
  for (int ni = 0; ni < 4; ++ni) {
    int col = n0 + wn + ni * 16 + l15;
    if (col >= Nreal) continue;
    int bcol = permb ? (((col & 3) << 9) | (col >> 2)) : col;
    float bs = bias ? bias[bcol] : 0.0f;
    for (int mi = 0; mi < 4; ++mi) {
      int rb = m0 + wm + mi * 16 + l4 * 4;
      facc v = acc[mi][ni];
      C[(size_t)(rb + 0) * ldc + col] = v[0] + bs;
      C[(size_t)(rb + 1) * ldc + col] = v[1] + bs;
      C[(size_t)(rb + 2) * ldc + col] = v[2] + bs;
      C[(size_t)(rb + 3) * ldc + col] = v[3] + bs;
    }
  }
}

// h dataflow buffer: u64 hbuf[slot][4096]; slot = state_version + offset.
// Element pi=(bb*512+col)/2 packs (hi_even|hi_odd<<16) | (lo_even|lo_odd<<16)<<32.
// Slots are written exactly once; sentinel-filled by k_fill each launch.

// ---------------- single-cell LSTM recurrence (persistent, NBLK x 512, U in VGPRs)
// Pure dataflow: consumers poll the h slot for step s (no barrier/flags).
__global__ __launch_bounds__(512, 1) void k_rec(const float* __restrict__ XW,
                                                const short* __restrict__ UT,
                                                const float* __restrict__ hinit,
                                                const float* __restrict__ cinit,
                                                u64* __restrict__ hbuf,   // [128][4096]
                                                float* __restrict__ hfin,
                                                float* __restrict__ cfin,
                                                short* __restrict__ seq_bf) {
  __shared__ short lh[2][16][520];
  __shared__ float zt[8][16][20];
  const int tid = threadIdx.x;
  const int wv = tid >> 6, lane = tid & 63;
  const int l15 = lane & 15, l4 = lane >> 4;
  const int kh = wv >> 2;                       // k-half 0/1
  const int gw = blockIdx.x * 4 + (wv & 3);     // 0..127
  const int bb = lane >> 2, jj = lane & 3;
  const int hidx = gw * 4 + jj;

  bfrag ur[8];                                  // U slice in VGPRs
  {
    const short* ub = UT + (size_t)(gw * 16 + l15) * Hq + kh * 256 + l4 * 8;
    #pragma unroll
    for (int ks = 0; ks < 8; ++ks) ur[ks] = *(const bfrag*)&ub[ks * 32];
  }
  float c = 0.0f;
  if (wv < 4) {
    c = cinit ? cinit[bb * Hq + hidx] : 0.0f;
    float hv = hinit ? hinit[bb * Hq + hidx] : 0.0f;
    int hi_ = (int)(unsigned short)f2bf(hv);
    int lo_ = (int)(unsigned short)f2bf(hv - bf2f((short)hi_));
    int hi2 = __shfl_xor(hi_, 1), lo2 = __shfl_xor(lo_, 1);
    if ((jj & 1) == 0) {
      u64 v = (u64)((u32)hi_ | ((u32)hi2 << 16)) | ((u64)((u32)lo_ | ((u32)lo2 << 16)) << 32);
      ic_store64(&hbuf[(bb * Hq + hidx) >> 1], v);   // slot 0 = state[-1]
    }
  }

  for (int s = 0; s < Tq; ++s) {
    f32x4 xg = {};
    if (wv < 4) xg = *(const f32x4*)&XW[(size_t)(s * Bq + bb) * G4H + hidx * 4];  // prefetch
    // ---- dataflow poll of slot s (state s-1)
    const u64* hsrc = hbuf + (size_t)s * 4096;
    u64 v[8];
    for (;;) {
      #pragma unroll
      for (int it = 0; it < 8; ++it) v[it] = ic_load64(&hsrc[it * 512 + tid]);
      u32 bad = 0;
      #pragma unroll
      for (int it = 0; it < 8; ++it) bad |= (((u32)v[it] & 0xFFFFu) == SENTW);
      if (!bad) break;
      __builtin_amdgcn_s_sleep(1);
    }
    #pragma unroll
    for (int it = 0; it < 8; ++it) {
      int i = it * 512 + tid;
      int b = i >> 8, bo = (i & 255) * 4;
      *(u32*)swz(&lh[0][0][0], b, bo) = (u32)v[it];
      *(u32*)swz(&lh[1][0][0], b, bo) = (u32)(v[it] >> 32);
    }
    __syncthreads();
    facc a0 = {}, a1 = {};
    #pragma unroll
    for (int ks = 0; ks < 8; ++ks) {
      int bo = kh * 512 + ks * 64 + l4 * 16;
      bfrag ah = *(const bfrag*)swz(&lh[0][0][0], l15, bo);
      bfrag al = *(const bfrag*)swz(&lh[1][0][0], l15, bo);
      a0 = __builtin_amdgcn_mfma_f32_16x16x32_bf16(ah, ur[ks], a0, 0, 0, 0);
      a1 = __builtin_amdgcn_mfma_f32_16x16x32_bf16(al, ur[ks], a1, 0, 0, 0);
    }
    a0 += a1;
    *(f32x4*)&zt[wv][l15][l4 * 4] = a0;
    __syncthreads();
    if (wv < 4) {
      float zi = zt[wv][4 * jj + 0][bb] + zt[wv + 4][4 * jj + 0][bb] + xg[0];
      float zf = zt[wv][4 * jj + 1][bb] + zt[wv + 4][4 * jj + 1][bb] + xg[1];
      float zg = zt[wv][4 * jj + 2][bb] + zt[wv + 4][4 * jj + 2][bb] + xg[2];
      float zo = zt[wv][4 * jj + 3][bb] + zt[wv + 4][4 * jj + 3][bb] + xg[3];
      c = sigm(zf) * c + sigm(zi) * tanhf(zg);
      float hN = sigm(zo) * tanhf(c);
      int hi_ = (int)(unsigned short)f2bf(hN);
      int lo_ = (int)(unsigned short)f2bf(hN - bf2f((short)hi_));
      int hi2 = __shfl_xor(hi_, 1), lo2 = __shfl_xor(lo_, 1);
      if (s < Tq - 1 && (jj & 1) == 0) {
        u64 v2 = (u64)((u32)hi_ | ((u32)hi2 << 16)) | ((u64)((u32)lo_ | ((u32)lo2 << 16)) << 32);
        ic_store64(&hbuf[(size_t)(s + 1) * 4096 + ((bb * Hq + hidx) >> 1)], v2);
      }
      seq_bf[(size_t)(s * Bq + bb) * Hq + hidx] = (short)hi_;
      if (s == Tq - 1) { hfin[bb * Hq + hidx] = hN; cfin[bb * Hq + hidx] = c; }
    }
  }
}

// ---------------- decoder: cells A,B skewed; dataflow sync; epilogues on wave halves
// hA slots: state s -> slot s+1 (0..128). hB slots: state s -> slot s+2 (0..128).
__global__ __launch_bounds__(512, 1) void k_dec2(const float* __restrict__ XW,
                                                 const short* __restrict__ U1T,   // Ud1'
                                                 const short* __restrict__ W2T,   // Wd2'
                                                 const short* __restrict__ U2T,   // Ud2'
                                                 const float* __restrict__ bd2,
                                                 const float* __restrict__ h1f, const float* __restrict__ c1f,
                                                 const float* __restrict__ h2f, const float* __restrict__ c2f,
                                                 u64* __restrict__ hAbuf, u64* __restrict__ hBbuf,
                                                 short* __restrict__ hBseq_bf, short* __restrict__ dec_bf) {
  __shared__ short lA[2][16][520];
  __shared__ short lB[2][16][520];
  __shared__ float ztA[8][16][20];
  __shared__ float ztB[8][16][20];
  const int tid = threadIdx.x;
  const int wv = tid >> 6, lane = tid & 63;
  const int l15 = lane & 15, l4 = lane >> 4;
  const int kh = wv >> 2;
  const int gw = blockIdx.x * 4 + (wv & 3);
  const int bb = lane >> 2, jj = lane & 3;
  const int hidx = gw * 4 + jj;

  bfrag u1r[8], w2r[8], u2r[8];                 // 96 VGPRs of weights
  {
    size_t ro = (size_t)(gw * 16 + l15) * Hq + kh * 256 + l4 * 8;
    #pragma unroll
    for (int ks = 0; ks < 8; ++ks) {
      u1r[ks] = *(const bfrag*)&U1T[ro + ks * 32];
      w2r[ks] = *(const bfrag*)&W2T[ro + ks * 32];
      u2r[ks] = *(const bfrag*)&U2T[ro + ks * 32];
    }
  }
  float cc = 0.0f, bdi = 0, bdf = 0, bdg = 0, bdo = 0;
  {
    const float* cf = (wv < 4) ? c1f : c2f;
    const float* hf = (wv < 4) ? h1f : h2f;
    cc = cf[bb * Hq + hidx];
    float hv = hf[bb * Hq + hidx];
    int hi_ = (int)(unsigned short)f2bf(hv);
    int lo_ = (int)(unsigned short)f2bf(hv - bf2f((short)hi_));
    int hi2 = __shfl_xor(hi_, 1), lo2 = __shfl_xor(lo_, 1);
    if ((jj & 1) == 0) {
      u64 v = (u64)((u32)hi_ | ((u32)hi2 << 16)) | ((u64)((u32)lo_ | ((u32)lo2 << 16)) << 32);
      int pi = (bb * Hq + hidx) >> 1;
      if (wv < 4) {
        ic_store64(&hAbuf[pi], v);                 // hA state[-1] -> slot 0
      } else {
        ic_store64(&hBbuf[pi], v);                 // hB state[-2] -> slot 0
        ic_store64(&hBbuf[4096 + pi], v);          // hB state[-1] -> slot 1
      }
    }
    if (wv >= 4) {
      bdi = bd2[hidx]; bdf = bd2[Hq + hidx];
      bdg = bd2[2 * Hq + hidx]; bdo = bd2[3 * Hq + hidx];
    }
  }

  for (int p = 0; p <= Tq; ++p) {
    f32x4 xg = {};
    if (wv < 4 && p < Tq) xg = *(const f32x4*)&XW[(size_t)(p * Bq + bb) * G4H + hidx * 4];
    // ---- dataflow poll of hA slot p (state p-1) and hB slot p (state p-2)
    const u64* asrc = hAbuf + (size_t)p * 4096;
    const u64* bsrc = hBbuf + (size_t)p * 4096;
    u64 va[8], vb[8];
    for (;;) {
      #pragma unroll
      for (int it = 0; it < 8; ++it) {
        va[it] = ic_load64(&asrc[it * 512 + tid]);
        vb[it] = ic_load64(&bsrc[it * 512 + tid]);
      }
      u32 bad = 0;
      #pragma unroll
      for (int it = 0; it < 8; ++it) {
        bad |= (((u32)va[it] & 0xFFFFu) == SENTW);
        bad |= (((u32)vb[it] & 0xFFFFu) == SENTW);
      }
      if (!bad) break;
      __builtin_amdgcn_s_sleep(1);
    }
    #pragma unroll
    for (int it = 0; it < 8; ++it) {
      int i = it * 512 + tid;
      int b = i >> 8, bo = (i & 255) * 4;
      *(u32*)swz(&lA[0][0][0], b, bo) = (u32)va[it];
      *(u32*)swz(&lA[1][0][0], b, bo) = (u32)(va[it] >> 32);
      *(u32*)swz(&lB[0][0][0], b, bo) = (u32)vb[it];
      *(u32*)swz(&lB[1][0][0], b, bo) = (u32)(vb[it] >> 32);
    }
    __syncthreads();

    facc a0 = {}, a1 = {}, b0 = {}, b1 = {}, b2 = {}, b3 = {};
    #pragma unroll
    for (int ks = 0; ks < 8; ++ks) {
      int bo = kh * 512 + ks * 64 + l4 * 16;
      bfrag ah = *(const bfrag*)swz(&lA[0][0][0], l15, bo);
      bfrag al = *(const bfrag*)swz(&lA[1][0][0], l15, bo);
      if (p < Tq) {
        a0 = __builtin_amdgcn_mfma_f32_16x16x32_bf16(ah, u1r[ks], a0, 0, 0, 0);
        a1 = __builtin_amdgcn_mfma_f32_16x16x32_bf16(al, u1r[ks], a1, 0, 0, 0);
      }
      if (p >= 1) {
        bfrag hh = *(const bfrag*)swz(&lB[0][0][0], l15, bo);
        bfrag hl = *(const bfrag*)swz(&lB[1][0][0], l15, bo);
        b0 = __builtin_amdgcn_mfma_f32_16x16x32_bf16(ah, w2r[ks], b0, 0, 0, 0);
        b1 = __builtin_amdgcn_mfma_f32_16x16x32_bf16(al, w2r[ks], b1, 0, 0, 0);
        b2 = __builtin_amdgcn_mfma_f32_16x16x32_bf16(hh, u2r[ks], b2, 0, 0, 0);
        b3 = __builtin_amdgcn_mfma_f32_16x16x32_bf16(hl, u2r[ks], b3, 0, 0, 0);
      }
    }
    if (p < Tq) { a0 += a1; *(f32x4*)&ztA[wv][l15][l4 * 4] = a0; }
    if (p >= 1) { b0 += b1; b0 += b2; b0 += b3; *(f32x4*)&ztB[wv][l15][l4 * 4] = b0; }
    __syncthreads();

    if (wv < 4 && p < Tq) {               // epilogue A (concurrent with B)
      float zi = ztA[wv][4 * jj + 0][bb] + ztA[wv + 4][4 * jj + 0][bb] + xg[0];
      float zf = ztA[wv][4 * jj + 1][bb] + ztA[wv + 4][4 * jj + 1][bb] + xg[1];
      float zg = ztA[wv][4 * jj + 2][bb] + ztA[wv + 4][4 * jj + 2][bb] + xg[2];
      float zo = ztA[wv][4 * jj + 3][bb] + ztA[wv + 4][4 * jj + 3][bb] + xg[3];
      cc = sigm(zf) * cc + sigm(zi) * tanhf(zg);
      float hN = sigm(zo) * tanhf(cc);
      int hi_ = (int)(unsigned short)f2bf(hN);
      int lo_ = (int)(unsigned short)f2bf(hN - bf2f((short)hi_));
      int hi2 = __shfl_xor(hi_, 1), lo2 = __shfl_xor(lo_, 1);
      if ((jj & 1) == 0) {
        u64 v = (u64)((u32)hi_ | ((u32)hi2 << 16)) | ((u64)((u32)lo_ | ((u32)lo2 << 16)) << 32);
        ic_store64(&hAbuf[(size_t)(p + 1) * 4096 + ((bb * Hq + hidx) >> 1)], v);
      }
    }
    if (wv >= 4 && p >= 1) {              // epilogue B
      int s = p - 1;
      int pw = wv - 4;
      float zi = ztB[pw][4 * jj + 0][bb] + ztB[wv][4 * jj + 0][bb] + bdi;
      float zf = ztB[pw][4 * jj + 1][bb] + ztB[wv][4 * jj + 1][bb] + bdf;
      float zg = ztB[pw][4 * jj + 2][bb] + ztB[wv][4 * jj + 2][bb] + bdg;
      float zo = ztB[pw][4 * jj + 3][bb] + ztB[wv][4 * jj + 3][bb] + bdo;
      cc = sigm(zf) * cc + sigm(zi) * tanhf(zg);
      float hN = sigm(zo) * tanhf(cc);
      int hi_ = (int)(unsigned short)f2bf(hN);
      int lo_ = (int)(unsigned short)f2bf(hN - bf2f((short)hi_));
      int hi2 = __shfl_xor(hi_, 1), lo2 = __shfl_xor(lo_, 1);
      if (p < Tq && (jj & 1) == 0) {
        u64 v = (u64)((u32)hi_ | ((u32)hi2 << 16)) | ((u64)((u32)lo_ | ((u32)lo2 << 16)) << 32);
        ic_store64(&hBbuf[(size_t)(p + 1) * 4096 + ((bb * Hq + hidx) >> 1)], v);
      }
      hBseq_bf[(size_t)(s * Bq + bb) * Hq + hidx] = (short)hi_;
      dec_bf[((size_t)bb * Tq + s) * (2 * Hq) + hidx] = (short)hi_;
    }
  }
}

// ---------------- batched attention over full seq2 (bf16 in/out; one block per (b,t))
__global__ __launch_bounds__(256) void k_attn(const short* __restrict__ seq2b,
                                              const short* __restrict__ hqb,
                                              short* __restrict__ decb) {
  int blk = blockIdx.x;
  int b = blk >> 7, t = blk & 127;
  __shared__ u32 q[256];         // 512 bf16 packed
  __shared__ float part[256];
  __shared__ float p[Tq];
  int tid = threadIdx.x;
  q[tid] = *(const u32*)&hqb[(size_t)(t * Bq + b) * Hq + tid * 2];
  __syncthreads();
  {
    int s = tid >> 1, half = tid & 1;
    const u32* row = (const u32*)&seq2b[(size_t)(s * Bq + b) * Hq + half * 256];
    const u32* qh = q + half * 128;
    float a = 0.0f;
    #pragma unroll 8
    for (int k = 0; k < 128; ++k) {
      u32 r = row[k], qq = qh[k];
      a += asf(r << 16) * asf(qq << 16) + asf(r & 0xFFFF0000u) * asf(qq & 0xFFFF0000u);
    }
    part[tid] = a;
  }
  __syncthreads();
  if (tid < 64) {
    float v0 = part[2 * tid] + part[2 * tid + 1];
    float v1 = part[2 * (tid + 64)] + part[2 * (tid + 64) + 1];
    float mx = fmaxf(v0, v1);
    for (int off = 32; off; off >>= 1) mx = fmaxf(mx, __shfl_xor(mx, off));
    float e0 = __expf(v0 - mx), e1 = __expf(v1 - mx);
    float sm = e0 + e1;
    for (int off = 32; off; off >>= 1) sm += __shfl_xor(sm, off);
    float inv = 1.0f / sm;
    p[tid] = e0 * inv; p[tid + 64] = e1 * inv;
  }
  __syncthreads();
  float c0 = 0.0f, c1 = 0.0f;
  for (int s = 0; s < Tq; ++s) {
    float ps = p[s];
    u32 r = *(const u32*)&seq2b[(size_t)(s * Bq + b) * Hq + tid * 2];
    c0 += ps * asf(r << 16);
    c1 += ps * asf(r & 0xFFFF0000u);
  }
  u32 o = ((u32)(unsigned short)f2bf(c0)) | (((u32)(unsigned short)f2bf(c1)) << 16);
  *(u32*)&decb[(size_t)(b * Tq + t) * (2 * Hq) + Hq + tid * 2] = o;
}

// ---------------- row softmax over VO=32001 (in-place on d_out)
__global__ __launch_bounds__(256) void k_softmax(float* __restrict__ L) {
  int row = blockIdx.x;
  float* p = L + (size_t)row * VO;
  int tid = threadIdx.x;
  float m = -3.0e38f, s = 0.0f;
  for (int i = tid; i < VO; i += 256) {
    float v = p[i];
    float mn = fmaxf(m, v);
    s = s * __expf(m - mn) + __expf(v - mn);
    m = mn;
  }
  __shared__ float sm[256], ss[256];
  sm[tid] = m; ss[tid] = s;
  __syncthreads();
  for (int off = 128; off; off >>= 1) {
    if (tid < off) {
      float m2 = sm[tid + off], s2 = ss[tid + off];
      float mn = fmaxf(sm[tid], m2);
      ss[tid] = ss[tid] * __expf(sm[tid] - mn) + s2 * __expf(m2 - mn);
      sm[tid] = mn;
    }
    __syncthreads();
  }
  float M = sm[0], IS = 1.0f / ss[0];
  for (int i = tid; i < VO; i += 256) {
    p[i] = __expf(p[i] - M) * IS;
  }
}

// =============================================================================
extern "C" void kernel_launch(void* const* d_in, const int* in_sizes, int n_in,
                              void* d_out, int out_size, void* d_ws, size_t ws_size,
                              hipStream_t stream) {
  const int*   tokens = (const int*)d_in[0];
  const float* emb    = (const float*)d_in[1];
  const float* W1     = (const float*)d_in[2];
  const float* U1     = (const float*)d_in[3];
  const float* b1     = (const float*)d_in[4];
  const float* W2     = (const float*)d_in[5];
  const float* U2     = (const float*)d_in[6];
  const float* b2     = (const float*)d_in[7];
  const float* Wd1    = (const float*)d_in[8];
  const float* Ud1    = (const float*)d_in[9];
  const float* bd1    = (const float*)d_in[10];
  const float* Wd2    = (const float*)d_in[11];
  const float* Ud2    = (const float*)d_in[12];
  const float* bd2    = (const float*)d_in[13];
  const float* Wo     = (const float*)d_in[14];
  const float* bo     = (const float*)d_in[15];
  float* out = (float*)d_out;

  size_t off = 0;
  char* base = (char*)d_ws;
  auto alloc = [&](size_t bytes) -> void* {
    void* p = base + off;
    off += (bytes + 255) & ~(size_t)255;
    return p;
  };
  short* x_bf    = (short*)alloc((size_t)MR * Dq * 2);
  short* W1T     = (short*)alloc((size_t)G4H * Dq * 2);
  short* W2T     = (short*)alloc((size_t)G4H * Hq * 2);
  short* Wd1T    = (short*)alloc((size_t)G4H * Hq * 2);
  short* WoT     = (short*)alloc((size_t)NPAD * (2 * Hq) * 2);
  short* U1T     = (short*)alloc((size_t)G4H * Hq * 2);
  short* U2T     = (short*)alloc((size_t)G4H * Hq * 2);
  short* Ud1T    = (short*)alloc((size_t)G4H * Hq * 2);
  short* Ud2T    = (short*)alloc((size_t)G4H * Hq * 2);
  short* Wd2T    = (short*)alloc((size_t)G4H * Hq * 2);
  float* XW      = (float*)alloc((size_t)MR * G4H * 4);       // reused x3
  short* seq1_bf = (short*)alloc((size_t)MR * Hq * 2);
  short* seq2_bf = (short*)alloc((size_t)MR * Hq * 2);
  short* hBseqbf = (short*)alloc((size_t)MR * Hq * 2);
  short* dec_bf  = (short*)alloc((size_t)MR * 2 * Hq * 2);
  // dataflow h buffers: enc1[128] enc2[128] hA[129] hB[129] slots of 4096 u64
  u64*   hflow   = (u64*)alloc((size_t)514 * 4096 * 8);
  u64*   h1buf   = hflow;
  u64*   h2buf   = hflow + (size_t)128 * 4096;
  u64*   hAbuf   = hflow + (size_t)256 * 4096;
  u64*   hBbuf   = hflow + (size_t)385 * 4096;
  float* h1f = (float*)alloc(BH * 4);
  float* c1f = (float*)alloc(BH * 4);
  float* h2f = (float*)alloc(BH * 4);
  float* c2f = (float*)alloc(BH * 4);
  (void)ws_size; (void)in_sizes; (void)n_in; (void)out_size;

  // sentinel-fill the dataflow buffers (per-launch reset; graph-replay safe)
  {
    int n = 514 * 4096;
    k_fill<<<(n + 255) / 256, 256, 0, stream>>>(hflow, n);
  }

  // weight transposes + bf16 conversion (+ gate-interleave perm on recurrent mats)
  k_transcvt<<<dim3(G4H / 32, Dq / 32), 256, 0, stream>>>(W1, W1T, Dq, G4H, 1);
  k_transcvt<<<dim3(G4H / 32, Hq / 32), 256, 0, stream>>>(W2, W2T, Hq, G4H, 1);
  k_transcvt<<<dim3(G4H / 32, Hq / 32), 256, 0, stream>>>(Wd1, Wd1T, Hq, G4H, 1);
  k_transcvt<<<dim3(G4H / 32, Hq / 32), 256, 0, stream>>>(U1, U1T, Hq, G4H, 1);
  k_transcvt<<<dim3(G4H / 32, Hq / 32), 256, 0, stream>>>(U2, U2T, Hq, G4H, 1);
  k_transcvt<<<dim3(G4H / 32, Hq / 32), 256, 0, stream>>>(Ud1, Ud1T, Hq, G4H, 1);
  k_transcvt<<<dim3(G4H / 32, Hq / 32), 256, 0, stream>>>(Ud2, Ud2T, Hq, G4H, 1);
  k_transcvt<<<dim3(G4H / 32, Hq / 32), 256, 0, stream>>>(Wd2, Wd2T, Hq, G4H, 1);
  k_transcvt<<<dim3(NPAD / 32, (2 * Hq) / 32), 256, 0, stream>>>(Wo, WoT, 2 * Hq, VO, 0);

  k_gather<<<MR, 256, 0, stream>>>(tokens, emb, x_bf);

  // encoder layer 1
  k_gemm<<<dim3(G4H / 128, MR / 128), 256, 0, stream>>>(x_bf, W1T, XW, b1, MR, G4H, Dq, G4H, 1);
  k_rec<<<NBLK, 512, 0, stream>>>(XW, U1T, nullptr, nullptr, h1buf, h1f, c1f, seq1_bf);

  // encoder layer 2 (init from layer-1 finals)
  k_gemm<<<dim3(G4H / 128, MR / 128), 256, 0, stream>>>(seq1_bf, W2T, XW, b2, MR, G4H, Hq, G4H, 1);
  k_rec<<<NBLK, 512, 0, stream>>>(XW, U2T, h1f, c1f, h2buf, h2f, c2f, seq2_bf);

  // decoder (cells A,B skewed; dataflow)
  k_gemm<<<dim3(G4H / 128, MR / 128), 256, 0, stream>>>(seq2_bf, Wd1T, XW, bd1, MR, G4H, Hq, G4H, 1);
  k_dec2<<<NBLK, 512, 0, stream>>>(XW, Ud1T, Wd2T, Ud2T, bd2, h1f, c1f, h2f, c2f,
                                   hAbuf, hBbuf, hBseqbf, dec_bf);

  // attention + logits + softmax
  k_attn<<<MR, 256, 0, stream>>>(seq2_bf, hBseqbf, dec_bf);
  k_gemm<<<dim3(NPAD / 128, MR / 128), 256, 0, stream>>>(dec_bf, WoT, out, bo, MR, VO, 2 * Hq, VO, 0);
  k_softmax<<<MR, 256, 0, stream>>>(out);
}

// Round 7
// 2306.693 us; speedup vs baseline: 1.6842x; 1.0020x over previous
//
#include <hip/hip_runtime.h>
#include <hip/hip_bf16.h>
#include <math.h>

// Model dims
#define Bq   16
#define Tq   128
#define Hq   512
#define Dq   256
#define G4H  2048            // 4*H
#define MR   2048            // B*T rows
#define VO   32001           // VOUT+1
#define NPAD 32128           // VO padded to multiple of 128
#define NWRK 32              // worker blocks for recurrence
#define BH   (Bq * Hq)       // 8192
#define SENTW 0x7FC0u        // bf16 NaN — impossible h value, used as sentinel
#define SENT64 0x7FC07FC07FC07FC0ull

typedef unsigned int u32;
typedef unsigned long long u64;
typedef __attribute__((ext_vector_type(4))) float f32x4;
typedef __attribute__((ext_vector_type(8))) short bfrag;   // 8 x bf16 (4 VGPRs)
typedef __attribute__((ext_vector_type(4))) float facc;    // mfma accumulator

__device__ __forceinline__ float bf2f(short s) {
  union { unsigned u; float f; } v; v.u = ((unsigned)(unsigned short)s) << 16; return v.f;
}
__device__ __forceinline__ short f2bf(float f) {
  union { float f; unsigned u; } v; v.f = f;
  unsigned r = (v.u + 0x7fffu + ((v.u >> 16) & 1u)) >> 16;
  return (short)r;
}
__device__ __forceinline__ float asf(u32 u) {
  union { u32 u; float f; } v; v.u = u; return v.f;
}
__device__ __forceinline__ float sigm(float x) { return 1.0f / (1.0f + expf(-x)); }

__device__ __forceinline__ void ic_store64(u64* p, u64 v) {
  __hip_atomic_store(p, v, __ATOMIC_RELAXED, __HIP_MEMORY_SCOPE_AGENT);
}
__device__ __forceinline__ u64 ic_load64(const u64* p) {
  return __hip_atomic_load(p, __ATOMIC_RELAXED, __HIP_MEMORY_SCOPE_AGENT);
}

// ---- heater: keeps a CU's VALU busy so the clock governor doesn't idle-throttle.
// Bounded (hard cap) + exits when workers signal done. Pure register work: no
// memory contention with the latency-critical recurrence.
__device__ void heater(const u32* done) {
  float a = (float)threadIdx.x * 1e-6f + 1.0f;
  float b = 1.0000001f, c = -1e-7f;
  asm volatile("" : "+v"(b), "+v"(c));          // opaque: keep the chain real
  for (int i = 0; i < 100000; ++i) {            // hard cap ~0.2 s — never hangs
    #pragma unroll
    for (int j = 0; j < 512; ++j) a = __builtin_fmaf(a, b, c);
    asm volatile("" : "+v"(a));
    if (__hip_atomic_load(done, __ATOMIC_RELAXED, __HIP_MEMORY_SCOPE_AGENT)) return;
  }
}

// ---- XOR-swizzled LDS addressing for a [16][520]-short plane (row stride 1040B)
__device__ __forceinline__ void* swz(void* plane, int row, int byteoff) {
  return (void*)((char*)plane + row * 1040 + (byteoff ^ ((row & 7) << 4)));
}

// ---------------- sentinel fill + zero fill (per-launch reset)
__global__ __launch_bounds__(256) void k_fill(u64* __restrict__ p, int n) {
  int i = blockIdx.x * 256 + threadIdx.x;
  if (i < n) p[i] = SENT64;
}
__global__ __launch_bounds__(64) void k_fill0(u32* __restrict__ p, int n) {
  int i = blockIdx.x * 64 + threadIdx.x;
  if (i < n) p[i] = 0u;
}

// ---------------- transpose + f32->bf16 (+ optional gate-interleave col perm)
__global__ __launch_bounds__(256) void k_transcvt(const float* __restrict__ in,
                                                  short* __restrict__ out,
                                                  int R, int N, int perm) {
  __shared__ float tile[32][33];
  int nb = blockIdx.x * 32, rb = blockIdx.y * 32;
  int tx = threadIdx.x & 31, ty = threadIdx.x >> 5;
  for (int i = 0; i < 4; ++i) {
    int r = rb + ty + i * 8;
    int n = nb + tx;
    tile[ty + i * 8][tx] = (n < N) ? in[(size_t)r * N + n] : 0.0f;
  }
  __syncthreads();
  for (int i = 0; i < 4; ++i) {
    int n = nb + ty + i * 8;
    int orow = perm ? (((n & 511) << 2) | (n >> 9)) : n;
    out[(size_t)orow * R + rb + tx] = f2bf(tile[tx][ty + i * 8]);
  }
}

// ---------------- embedding gather -> x_bf [T*B, D] bf16
__global__ __launch_bounds__(256) void k_gather(const int* __restrict__ tokens,
                                                const float* __restrict__ emb,
                                                short* __restrict__ xbf) {
  int row = blockIdx.x;                 // t*16+b
  int t = row >> 4, b = row & 15;
  int tok = tokens[b * Tq + t];
  xbf[(size_t)row * Dq + threadIdx.x] = f2bf(emb[(size_t)tok * Dq + threadIdx.x]);
}

// ---------------- bf16 MFMA GEMM: C[M,ldc] = A[M,K] @ BT[Npad,K]^T + bias
__global__ __launch_bounds__(256) void k_gemm(const short* __restrict__ A,
                                              const short* __restrict__ BT,
                                              float* __restrict__ C,
                                              const float* __restrict__ bias,
                                              int M, int Nreal, int K, int ldc,
                                              int permb) {
  __shared__ short lA[128 * 64];
  __shared__ short lB[128 * 64];
  const int tid = threadIdx.x;
  const int wave = tid >> 6, lane = tid & 63;
  const int l15 = lane & 15, l4 = lane >> 4;
  const int m0 = blockIdx.y * 128, n0 = blockIdx.x * 128;
  const int wm = (wave >> 1) * 64, wn = (wave & 1) * 64;
  facc acc[4][4] = {};

  for (int k0 = 0; k0 < K; k0 += 64) {
    __syncthreads();
    for (int i = 0; i < 4; ++i) {
      int c = i * 256 + wave * 64 + lane;
      int r = c >> 3, q = c & 7;
      int qs = q ^ (r & 7);
      const short* ga = A + (size_t)(m0 + r) * K + k0 + qs * 8;
      const short* gb = BT + (size_t)(n0 + r) * K + k0 + qs * 8;
      short* la = lA + (size_t)(i * 256 + wave * 64) * 8;
      short* lb = lB + (size_t)(i * 256 + wave * 64) * 8;
      __builtin_amdgcn_global_load_lds((const __attribute__((address_space(1))) u32*)ga,
                                       (__attribute__((address_space(3))) u32*)la, 16, 0, 0);
      __builtin_amdgcn_global_load_lds((const __attribute__((address_space(1))) u32*)gb,
                                       (__attribute__((address_space(3))) u32*)lb, 16, 0, 0);
    }
    __syncthreads();
    for (int ks = 0; ks < 2; ++ks) {
      bfrag a[4], b[4];
      for (int mi = 0; mi < 4; ++mi) {
        int r = wm + mi * 16 + l15;
        int qs = (ks * 4 + l4) ^ (r & 7);
        a[mi] = *(const bfrag*)&lA[r * 64 + qs * 8];
      }
      for (int ni = 0; ni < 4; ++ni) {
        int r = wn + ni * 16 + l15;
        int qs = (ks * 4 + l4) ^ (r & 7);
        b[ni] = *(const bfrag*)&lB[r * 64 + qs * 8];
      }
      for (int mi = 0; mi < 4; ++mi)
        for (int ni = 0; ni < 4; ++ni)
          acc[mi][ni] = __builtin_amdgcn_mfma_f32_16x16x32_bf16(a[mi], b[ni], acc[mi][ni], 0, 0, 0);
    }
  }
  for (int ni = 0; ni < 4; ++ni) {
    int col = n0 + wn + ni * 16 + l15;
    if (col >= Nreal) continue;
    int bcol = permb ? (((col & 3) << 9) | (col >> 2)) : col;
    float bs = bias ? bias[bcol] : 0.0f;
    for (int mi = 0; mi < 4; ++mi) {
      int rb = m0 + wm + mi * 16 + l4 * 4;
      facc v = acc[mi][ni];
      C[(size_t)(rb + 0) * ldc + col] = v[0] + bs;
      C[(size_t)(rb + 1) * ldc + col] = v[1] + bs;
      C[(size_t)(rb + 2) * ldc + col] = v[2] + bs;
      C[(size_t)(rb + 3) * ldc + col] = v[3] + bs;
    }
  }
}

// h dataflow buffer: u64 hbuf[slot][4096]; slot = state_version + offset.
// Element pi=(bb*512+col)/2 packs (hi_even|hi_odd<<16) | (lo_even|lo_odd<<16)<<32.
// Slots written exactly once; sentinel-filled by k_fill each launch.

// ---------------- single-cell LSTM recurrence (blocks 0..31 work, rest heat)
__global__ __launch_bounds__(512, 1) void k_rec(const float* __restrict__ XW,
                                                const short* __restrict__ UT,
                                                const float* __restrict__ hinit,
                                                const float* __restrict__ cinit,
                                                u64* __restrict__ hbuf,   // [128][4096]
                                                float* __restrict__ hfin,
                                                float* __restrict__ cfin,
                                                short* __restrict__ seq_bf,
                                                u32* __restrict__ done) {
  extern __shared__ u64 dynpad[];     // launch-sized pad: forces 1 block/CU
  (void)dynpad;
  __shared__ short lh[2][16][520];
  __shared__ float zt[8][16][20];
  if (blockIdx.x >= NWRK) { heater(done); return; }
  const int rank = blockIdx.x;
  const int tid = threadIdx.x;
  const int wv = tid >> 6, lane = tid & 63;
  const int l15 = lane & 15, l4 = lane >> 4;
  const int kh = wv >> 2;                       // k-half 0/1
  const int gw = rank * 4 + (wv & 3);           // 0..127
  const int bb = lane >> 2, jj = lane & 3;
  const int hidx = gw * 4 + jj;

  bfrag ur[8];                                  // U slice in VGPRs
  {
    const short* ub = UT + (size_t)(gw * 16 + l15) * Hq + kh * 256 + l4 * 8;
    #pragma unroll
    for (int ks = 0; ks < 8; ++ks) ur[ks] = *(const bfrag*)&ub[ks * 32];
  }
  float c = 0.0f;
  if (wv < 4) {
    c = cinit ? cinit[bb * Hq + hidx] : 0.0f;
    float hv = hinit ? hinit[bb * Hq + hidx] : 0.0f;
    int hi_ = (int)(unsigned short)f2bf(hv);
    int lo_ = (int)(unsigned short)f2bf(hv - bf2f((short)hi_));
    int hi2 = __shfl_xor(hi_, 1), lo2 = __shfl_xor(lo_, 1);
    if ((jj & 1) == 0) {
      u64 v = (u64)((u32)hi_ | ((u32)hi2 << 16)) | ((u64)((u32)lo_ | ((u32)lo2 << 16)) << 32);
      ic_store64(&hbuf[(bb * Hq + hidx) >> 1], v);   // slot 0 = state[-1]
    }
  }

  for (int s = 0; s < Tq; ++s) {
    f32x4 xg = {};
    if (wv < 4) xg = *(const f32x4*)&XW[(size_t)(s * Bq + bb) * G4H + hidx * 4];  // prefetch
    // ---- dataflow poll of slot s (state s-1)
    const u64* hsrc = hbuf + (size_t)s * 4096;
    u64 v[8];
    for (;;) {
      #pragma unroll
      for (int it = 0; it < 8; ++it) v[it] = ic_load64(&hsrc[it * 512 + tid]);
      u32 bad = 0;
      #pragma unroll
      for (int it = 0; it < 8; ++it) bad |= (((u32)v[it] & 0xFFFFu) == SENTW);
      if (!bad) break;
      __builtin_amdgcn_s_sleep(1);
    }
    #pragma unroll
    for (int it = 0; it < 8; ++it) {
      int i = it * 512 + tid;
      int b = i >> 8, bo = (i & 255) * 4;
      *(u32*)swz(&lh[0][0][0], b, bo) = (u32)v[it];
      *(u32*)swz(&lh[1][0][0], b, bo) = (u32)(v[it] >> 32);
    }
    __syncthreads();
    facc a0 = {}, a1 = {};
    #pragma unroll
    for (int ks = 0; ks < 8; ++ks) {
      int bo = kh * 512 + ks * 64 + l4 * 16;
      bfrag ah = *(const bfrag*)swz(&lh[0][0][0], l15, bo);
      bfrag al = *(const bfrag*)swz(&lh[1][0][0], l15, bo);
      a0 = __builtin_amdgcn_mfma_f32_16x16x32_bf16(ah, ur[ks], a0, 0, 0, 0);
      a1 = __builtin_amdgcn_mfma_f32_16x16x32_bf16(al, ur[ks], a1, 0, 0, 0);
    }
    a0 += a1;
    *(f32x4*)&zt[wv][l15][l4 * 4] = a0;
    __syncthreads();
    if (wv < 4) {
      float zi = zt[wv][4 * jj + 0][bb] + zt[wv + 4][4 * jj + 0][bb] + xg[0];
      float zf = zt[wv][4 * jj + 1][bb] + zt[wv + 4][4 * jj + 1][bb] + xg[1];
      float zg = zt[wv][4 * jj + 2][bb] + zt[wv + 4][4 * jj + 2][bb] + xg[2];
      float zo = zt[wv][4 * jj + 3][bb] + zt[wv + 4][4 * jj + 3][bb] + xg[3];
      c = sigm(zf) * c + sigm(zi) * tanhf(zg);
      float hN = sigm(zo) * tanhf(c);
      int hi_ = (int)(unsigned short)f2bf(hN);
      int lo_ = (int)(unsigned short)f2bf(hN - bf2f((short)hi_));
      int hi2 = __shfl_xor(hi_, 1), lo2 = __shfl_xor(lo_, 1);
      if (s < Tq - 1 && (jj & 1) == 0) {
        u64 v2 = (u64)((u32)hi_ | ((u32)hi2 << 16)) | ((u64)((u32)lo_ | ((u32)lo2 << 16)) << 32);
        ic_store64(&hbuf[(size_t)(s + 1) * 4096 + ((bb * Hq + hidx) >> 1)], v2);
      }
      seq_bf[(size_t)(s * Bq + bb) * Hq + hidx] = (short)hi_;
      if (s == Tq - 1) { hfin[bb * Hq + hidx] = hN; cfin[bb * Hq + hidx] = c; }
    }
  }
  if (rank == 0 && tid == 0)
    __hip_atomic_store(done, 1u, __ATOMIC_RELAXED, __HIP_MEMORY_SCOPE_AGENT);
}

// ---------------- decoder: cells A,B skewed; dataflow sync; epilogues on wave halves
// hA slots: state s -> slot s+1 (0..128). hB slots: state s -> slot s+2 (0..129).
__global__ __launch_bounds__(512, 1) void k_dec2(const float* __restrict__ XW,
                                                 const short* __restrict__ U1T,   // Ud1'
                                                 const short* __restrict__ W2T,   // Wd2'
                                                 const short* __restrict__ U2T,   // Ud2'
                                                 const float* __restrict__ bd2,
                                                 const float* __restrict__ h1f, const float* __restrict__ c1f,
                                                 const float* __restrict__ h2f, const float* __restrict__ c2f,
                                                 u64* __restrict__ hAbuf, u64* __restrict__ hBbuf,
                                                 short* __restrict__ hBseq_bf, short* __restrict__ dec_bf,
                                                 u32* __restrict__ done) {
  __shared__ short lA[2][16][520];
  __shared__ short lB[2][16][520];
  __shared__ float ztA[8][16][20];
  __shared__ float ztB[8][16][20];
  if (blockIdx.x >= NWRK) { heater(done); return; }
  const int rank = blockIdx.x;
  const int tid = threadIdx.x;
  const int wv = tid >> 6, lane = tid & 63;
  const int l15 = lane & 15, l4 = lane >> 4;
  const int kh = wv >> 2;
  const int gw = rank * 4 + (wv & 3);
  const int bb = lane >> 2, jj = lane & 3;
  const int hidx = gw * 4 + jj;

  bfrag u1r[8], w2r[8], u2r[8];                 // 96 VGPRs of weights
  {
    size_t ro = (size_t)(gw * 16 + l15) * Hq + kh * 256 + l4 * 8;
    #pragma unroll
    for (int ks = 0; ks < 8; ++ks) {
      u1r[ks] = *(const bfrag*)&U1T[ro + ks * 32];
      w2r[ks] = *(const bfrag*)&W2T[ro + ks * 32];
      u2r[ks] = *(const bfrag*)&U2T[ro + ks * 32];
    }
  }
  float cc = 0.0f, bdi = 0, bdf = 0, bdg = 0, bdo = 0;
  {
    const float* cf = (wv < 4) ? c1f : c2f;
    const float* hf = (wv < 4) ? h1f : h2f;
    cc = cf[bb * Hq + hidx];
    float hv = hf[bb * Hq + hidx];
    int hi_ = (int)(unsigned short)f2bf(hv);
    int lo_ = (int)(unsigned short)f2bf(hv - bf2f((short)hi_));
    int hi2 = __shfl_xor(hi_, 1), lo2 = __shfl_xor(lo_, 1);
    if ((jj & 1) == 0) {
      u64 v = (u64)((u32)hi_ | ((u32)hi2 << 16)) | ((u64)((u32)lo_ | ((u32)lo2 << 16)) << 32);
      int pi = (bb * Hq + hidx) >> 1;
      if (wv < 4) {
        ic_store64(&hAbuf[pi], v);                 // hA state[-1] -> slot 0
      } else {
        ic_store64(&hBbuf[pi], v);                 // hB state[-2] -> slot 0
        ic_store64(&hBbuf[4096 + pi], v);          // hB state[-1] -> slot 1
      }
    }
    if (wv >= 4) {
      bdi = bd2[hidx]; bdf = bd2[Hq + hidx];
      bdg = bd2[2 * Hq + hidx]; bdo = bd2[3 * Hq + hidx];
    }
  }

  for (int p = 0; p <= Tq; ++p) {
    f32x4 xg = {};
    if (wv < 4 && p < Tq) xg = *(const f32x4*)&XW[(size_t)(p * Bq + bb) * G4H + hidx * 4];
    // ---- dataflow poll of hA slot p (state p-1) and hB slot p (state p-2)
    const u64* asrc = hAbuf + (size_t)p * 4096;
    const u64* bsrc = hBbuf + (size_t)p * 4096;
    u64 va[8], vb[8];
    for (;;) {
      #pragma unroll
      for (int it = 0; it < 8; ++it) {
        va[it] = ic_load64(&asrc[it * 512 + tid]);
        vb[it] = ic_load64(&bsrc[it * 512 + tid]);
      }
      u32 bad = 0;
      #pragma unroll
      for (int it = 0; it < 8; ++it) {
        bad |= (((u32)va[it] & 0xFFFFu) == SENTW);
        bad |= (((u32)vb[it] & 0xFFFFu) == SENTW);
      }
      if (!bad) break;
      __builtin_amdgcn_s_sleep(1);
    }
    #pragma unroll
    for (int it = 0; it < 8; ++it) {
      int i = it * 512 + tid;
      int b = i >> 8, bo = (i & 255) * 4;
      *(u32*)swz(&lA[0][0][0], b, bo) = (u32)va[it];
      *(u32*)swz(&lA[1][0][0], b, bo) = (u32)(va[it] >> 32);
      *(u32*)swz(&lB[0][0][0], b, bo) = (u32)vb[it];
      *(u32*)swz(&lB[1][0][0], b, bo) = (u32)(vb[it] >> 32);
    }
    __syncthreads();

    facc a0 = {}, a1 = {}, b0 = {}, b1 = {}, b2 = {}, b3 = {};
    #pragma unroll
    for (int ks = 0; ks < 8; ++ks) {
      int bo = kh * 512 + ks * 64 + l4 * 16;
      bfrag ah = *(const bfrag*)swz(&lA[0][0][0], l15, bo);
      bfrag al = *(const bfrag*)swz(&lA[1][0][0], l15, bo);
      if (p < Tq) {
        a0 = __builtin_amdgcn_mfma_f32_16x16x32_bf16(ah, u1r[ks], a0, 0, 0, 0);
        a1 = __builtin_amdgcn_mfma_f32_16x16x32_bf16(al, u1r[ks], a1, 0, 0, 0);
      }
      if (p >= 1) {
        bfrag hh = *(const bfrag*)swz(&lB[0][0][0], l15, bo);
        bfrag hl = *(const bfrag*)swz(&lB[1][0][0], l15, bo);
        b0 = __builtin_amdgcn_mfma_f32_16x16x32_bf16(ah, w2r[ks], b0, 0, 0, 0);
        b1 = __builtin_amdgcn_mfma_f32_16x16x32_bf16(al, w2r[ks], b1, 0, 0, 0);
        b2 = __builtin_amdgcn_mfma_f32_16x16x32_bf16(hh, u2r[ks], b2, 0, 0, 0);
        b3 = __builtin_amdgcn_mfma_f32_16x16x32_bf16(hl, u2r[ks], b3, 0, 0, 0);
      }
    }
    if (p < Tq) { a0 += a1; *(f32x4*)&ztA[wv][l15][l4 * 4] = a0; }
    if (p >= 1) { b0 += b1; b0 += b2; b0 += b3; *(f32x4*)&ztB[wv][l15][l4 * 4] = b0; }
    __syncthreads();

    if (wv < 4 && p < Tq) {               // epilogue A (concurrent with B)
      float zi = ztA[wv][4 * jj + 0][bb] + ztA[wv + 4][4 * jj + 0][bb] + xg[0];
      float zf = ztA[wv][4 * jj + 1][bb] + ztA[wv + 4][4 * jj + 1][bb] + xg[1];
      float zg = ztA[wv][4 * jj + 2][bb] + ztA[wv + 4][4 * jj + 2][bb] + xg[2];
      float zo = ztA[wv][4 * jj + 3][bb] + ztA[wv + 4][4 * jj + 3][bb] + xg[3];
      cc = sigm(zf) * cc + sigm(zi) * tanhf(zg);
      float hN = sigm(zo) * tanhf(cc);
      int hi_ = (int)(unsigned short)f2bf(hN);
      int lo_ = (int)(unsigned short)f2bf(hN - bf2f((short)hi_));
      int hi2 = __shfl_xor(hi_, 1), lo2 = __shfl_xor(lo_, 1);
      if ((jj & 1) == 0) {
        u64 v = (u64)((u32)hi_ | ((u32)hi2 << 16)) | ((u64)((u32)lo_ | ((u32)lo2 << 16)) << 32);
        ic_store64(&hAbuf[(size_t)(p + 1) * 4096 + ((bb * Hq + hidx) >> 1)], v);
      }
    }
    if (wv >= 4 && p >= 1) {              // epilogue B
      int s = p - 1;
      int pw = wv - 4;
      float zi = ztB[pw][4 * jj + 0][bb] + ztB[wv][4 * jj + 0][bb] + bdi;
      float zf = ztB[pw][4 * jj + 1][bb] + ztB[wv][4 * jj + 1][bb] + bdf;
      float zg = ztB[pw][4 * jj + 2][bb] + ztB[wv][4 * jj + 2][bb] + bdg;
      float zo = ztB[pw][4 * jj + 3][bb] + ztB[wv][4 * jj + 3][bb] + bdo;
      cc = sigm(zf) * cc + sigm(zi) * tanhf(zg);
      float hN = sigm(zo) * tanhf(cc);
      int hi_ = (int)(unsigned short)f2bf(hN);
      int lo_ = (int)(unsigned short)f2bf(hN - bf2f((short)hi_));
      int hi2 = __shfl_xor(hi_, 1), lo2 = __shfl_xor(lo_, 1);
      if (p < Tq && (jj & 1) == 0) {
        u64 v = (u64)((u32)hi_ | ((u32)hi2 << 16)) | ((u64)((u32)lo_ | ((u32)lo2 << 16)) << 32);
        ic_store64(&hBbuf[(size_t)(p + 1) * 4096 + ((bb * Hq + hidx) >> 1)], v);
      }
      hBseq_bf[(size_t)(s * Bq + bb) * Hq + hidx] = (short)hi_;
      dec_bf[((size_t)bb * Tq + s) * (2 * Hq) + hidx] = (short)hi_;
    }
  }
  if (rank == 0 && tid == 0)
    __hip_atomic_store(done, 1u, __ATOMIC_RELAXED, __HIP_MEMORY_SCOPE_AGENT);
}

// ---------------- batched attention over full seq2 (bf16 in/out; one block per (b,t))
__global__ __launch_bounds__(256) void k_attn(const short* __restrict__ seq2b,
                                              const short* __restrict__ hqb,
                                              short* __restrict__ decb) {
  int blk = blockIdx.x;
  int b = blk >> 7, t = blk & 127;
  __shared__ u32 q[256];         // 512 bf16 packed
  __shared__ float part[256];
  __shared__ float p[Tq];
  int tid = threadIdx.x;
  q[tid] = *(const u32*)&hqb[(size_t)(t * Bq + b) * Hq + tid * 2];
  __syncthreads();
  {
    int s = tid >> 1, half = tid & 1;
    const u32* row = (const u32*)&seq2b[(size_t)(s * Bq + b) * Hq + half * 256];
    const u32* qh = q + half * 128;
    float a = 0.0f;
    #pragma unroll 8
    for (int k = 0; k < 128; ++k) {
      u32 r = row[k], qq = qh[k];
      a += asf(r << 16) * asf(qq << 16) + asf(r & 0xFFFF0000u) * asf(qq & 0xFFFF0000u);
    }
    part[tid] = a;
  }
  __syncthreads();
  if (tid < 64) {
    float v0 = part[2 * tid] + part[2 * tid + 1];
    float v1 = part[2 * (tid + 64)] + part[2 * (tid + 64) + 1];
    float mx = fmaxf(v0, v1);
    for (int off = 32; off; off >>= 1) mx = fmaxf(mx, __shfl_xor(mx, off));
    float e0 = __expf(v0 - mx), e1 = __expf(v1 - mx);
    float sm = e0 + e1;
    for (int off = 32; off; off >>= 1) sm += __shfl_xor(sm, off);
    float inv = 1.0f / sm;
    p[tid] = e0 * inv; p[tid + 64] = e1 * inv;
  }
  __syncthreads();
  float c0 = 0.0f, c1 = 0.0f;
  for (int s = 0; s < Tq; ++s) {
    float ps = p[s];
    u32 r = *(const u32*)&seq2b[(size_t)(s * Bq + b) * Hq + tid * 2];
    c0 += ps * asf(r << 16);
    c1 += ps * asf(r & 0xFFFF0000u);
  }
  u32 o = ((u32)(unsigned short)f2bf(c0)) | (((u32)(unsigned short)f2bf(c1)) << 16);
  *(u32*)&decb[(size_t)(b * Tq + t) * (2 * Hq) + Hq + tid * 2] = o;
}

// ---------------- row softmax over VO=32001 (in-place on d_out)
__global__ __launch_bounds__(256) void k_softmax(float* __restrict__ L) {
  int row = blockIdx.x;
  float* p = L + (size_t)row * VO;
  int tid = threadIdx.x;
  float m = -3.0e38f, s = 0.0f;
  for (int i = tid; i < VO; i += 256) {
    float v = p[i];
    float mn = fmaxf(m, v);
    s = s * __expf(m - mn) + __expf(v - mn);
    m = mn;
  }
  __shared__ float sm[256], ss[256];
  sm[tid] = m; ss[tid] = s;
  __syncthreads();
  for (int off = 128; off; off >>= 1) {
    if (tid < off) {
      float m2 = sm[tid + off], s2 = ss[tid + off];
      float mn = fmaxf(sm[tid], m2);
      ss[tid] = ss[tid] * __expf(sm[tid] - mn) + s2 * __expf(m2 - mn);
      sm[tid] = mn;
    }
    __syncthreads();
  }
  float M = sm[0], IS = 1.0f / ss[0];
  for (int i = tid; i < VO; i += 256) {
    p[i] = __expf(p[i] - M) * IS;
  }
}

// =============================================================================
extern "C" void kernel_launch(void* const* d_in, const int* in_sizes, int n_in,
                              void* d_out, int out_size, void* d_ws, size_t ws_size,
                              hipStream_t stream) {
  const int*   tokens = (const int*)d_in[0];
  const float* emb    = (const float*)d_in[1];
  const float* W1     = (const float*)d_in[2];
  const float* U1     = (const float*)d_in[3];
  const float* b1     = (const float*)d_in[4];
  const float* W2     = (const float*)d_in[5];
  const float* U2     = (const float*)d_in[6];
  const float* b2     = (const float*)d_in[7];
  const float* Wd1    = (const float*)d_in[8];
  const float* Ud1    = (const float*)d_in[9];
  const float* bd1    = (const float*)d_in[10];
  const float* Wd2    = (const float*)d_in[11];
  const float* Ud2    = (const float*)d_in[12];
  const float* bd2    = (const float*)d_in[13];
  const float* Wo     = (const float*)d_in[14];
  const float* bo     = (const float*)d_in[15];
  float* out = (float*)d_out;

  size_t off = 0;
  char* base = (char*)d_ws;
  auto alloc = [&](size_t bytes) -> void* {
    void* p = base + off;
    off += (bytes + 255) & ~(size_t)255;
    return p;
  };
  u32*   done3   = (u32*)alloc(256);           // done flags for heater exit
  short* x_bf    = (short*)alloc((size_t)MR * Dq * 2);
  short* W1T     = (short*)alloc((size_t)G4H * Dq * 2);
  short* W2T     = (short*)alloc((size_t)G4H * Hq * 2);
  short* Wd1T    = (short*)alloc((size_t)G4H * Hq * 2);
  short* WoT     = (short*)alloc((size_t)NPAD * (2 * Hq) * 2);
  short* U1T     = (short*)alloc((size_t)G4H * Hq * 2);
  short* U2T     = (short*)alloc((size_t)G4H * Hq * 2);
  short* Ud1T    = (short*)alloc((size_t)G4H * Hq * 2);
  short* Ud2T    = (short*)alloc((size_t)G4H * Hq * 2);
  short* Wd2T    = (short*)alloc((size_t)G4H * Hq * 2);
  float* XW      = (float*)alloc((size_t)MR * G4H * 4);       // reused x3
  short* seq1_bf = (short*)alloc((size_t)MR * Hq * 2);
  short* seq2_bf = (short*)alloc((size_t)MR * Hq * 2);
  short* hBseqbf = (short*)alloc((size_t)MR * Hq * 2);
  short* dec_bf  = (short*)alloc((size_t)MR * 2 * Hq * 2);
  // dataflow h buffers: enc1[128] enc2[128] hA[129] hB[129] slots of 4096 u64
  u64*   hflow   = (u64*)alloc((size_t)514 * 4096 * 8);
  u64*   h1buf   = hflow;
  u64*   h2buf   = hflow + (size_t)128 * 4096;
  u64*   hAbuf   = hflow + (size_t)256 * 4096;
  u64*   hBbuf   = hflow + (size_t)385 * 4096;
  float* h1f = (float*)alloc(BH * 4);
  float* c1f = (float*)alloc(BH * 4);
  float* h2f = (float*)alloc(BH * 4);
  float* c2f = (float*)alloc(BH * 4);
  (void)ws_size; (void)in_sizes; (void)n_in; (void)out_size;

  // per-launch reset: done flags + sentinel fill (graph-replay safe)
  k_fill0<<<1, 64, 0, stream>>>(done3, 64);
  {
    int n = 514 * 4096;
    k_fill<<<(n + 255) / 256, 256, 0, stream>>>(hflow, n);
  }

  // weight transposes + bf16 conversion (+ gate-interleave perm on recurrent mats)
  k_transcvt<<<dim3(G4H / 32, Dq / 32), 256, 0, stream>>>(W1, W1T, Dq, G4H, 1);
  k_transcvt<<<dim3(G4H / 32, Hq / 32), 256, 0, stream>>>(W2, W2T, Hq, G4H, 1);
  k_transcvt<<<dim3(G4H / 32, Hq / 32), 256, 0, stream>>>(Wd1, Wd1T, Hq, G4H, 1);
  k_transcvt<<<dim3(G4H / 32, Hq / 32), 256, 0, stream>>>(U1, U1T, Hq, G4H, 1);
  k_transcvt<<<dim3(G4H / 32, Hq / 32), 256, 0, stream>>>(U2, U2T, Hq, G4H, 1);
  k_transcvt<<<dim3(G4H / 32, Hq / 32), 256, 0, stream>>>(Ud1, Ud1T, Hq, G4H, 1);
  k_transcvt<<<dim3(G4H / 32, Hq / 32), 256, 0, stream>>>(Ud2, Ud2T, Hq, G4H, 1);
  k_transcvt<<<dim3(G4H / 32, Hq / 32), 256, 0, stream>>>(Wd2, Wd2T, Hq, G4H, 1);
  k_transcvt<<<dim3(NPAD / 32, (2 * Hq) / 32), 256, 0, stream>>>(Wo, WoT, 2 * Hq, VO, 0);

  k_gather<<<MR, 256, 0, stream>>>(tokens, emb, x_bf);

  // encoder layer 1 (blocks 0..31 work; 32..255 heat the clock governor)
  k_gemm<<<dim3(G4H / 128, MR / 128), 256, 0, stream>>>(x_bf, W1T, XW, b1, MR, G4H, Dq, G4H, 1);
  k_rec<<<256, 512, 40960, stream>>>(XW, U1T, nullptr, nullptr, h1buf, h1f, c1f, seq1_bf, done3);

  // encoder layer 2 (init from layer-1 finals)
  k_gemm<<<dim3(G4H / 128, MR / 128), 256, 0, stream>>>(seq1_bf, W2T, XW, b2, MR, G4H, Hq, G4H, 1);
  k_rec<<<256, 512, 40960, stream>>>(XW, U2T, h1f, c1f, h2buf, h2f, c2f, seq2_bf, done3 + 16);

  // decoder (cells A,B skewed; dataflow + heaters)
  k_gemm<<<dim3(G4H / 128, MR / 128), 256, 0, stream>>>(seq2_bf, Wd1T, XW, bd1, MR, G4H, Hq, G4H, 1);
  k_dec2<<<256, 512, 0, stream>>>(XW, Ud1T, Wd2T, Ud2T, bd2, h1f, c1f, h2f, c2f,
                                  hAbuf, hBbuf, hBseqbf, dec_bf, done3 + 32);

  // attention + logits + softmax
  k_attn<<<MR, 256, 0, stream>>>(seq2_bf, hBseqbf, dec_bf);
  k_gemm<<<dim3(NPAD / 128, MR / 128), 256, 0, stream>>>(dec_bf, WoT, out, bo, MR, VO, 2 * Hq, VO, 0);
  k_softmax<<<MR, 256, 0, stream>>>(out);
}